// Round 17
// baseline (3140.034 us; speedup 1.0000x reference)
//
#include <hip/hip_runtime.h>
#include <float.h>
#include <math.h>

// Problem constants
#define B_ 16
#define N_ 4096
#define S_ 1024
#define K_ 32
#define CIN0 67              // 3 + 64
#define NBS (B_ * S_)        // 16384
#define NEWXYZ_FLOATS (B_ * S_ * 3)  // 49152
#define AST 68               // LDS activation row stride
#define AQ (K_ * AST)        // 2176 floats per query
#define QB 4                 // queries per pass-block (wave = query)

// ---------------- helpers ----------------

__device__ __forceinline__ float sqdist3(float x, float y, float z,
                                         float cx, float cy, float cz) {
#pragma clang fp contract(off)
  float dx = x - cx, dy = y - cy, dz = z - cz;
  float s = dx * dx;
  s = s + dy * dy;
  s = s + dz * dz;
  return s;
}

__device__ __forceinline__ float knn_dist(float c2, float cx, float cy, float cz,
                                          float x, float y, float z) {
#pragma clang fp contract(off)
  float dot = cx * x; dot = dot + cy * y; dot = dot + cz * z;
  float x2 = x * x;   x2 = x2 + y * y;   x2 = x2 + z * z;
  float d = c2 - 2.0f * dot;
  d = d + x2;
  return d;
}

// ---- DPP cross-lane (gfx9: row_shr:N=0x110|N, row_bcast15=0x142, row_bcast31=0x143) ----
template <int CTRL>
__device__ __forceinline__ float dpp_f(float v, float oldv) {
  return __int_as_float(__builtin_amdgcn_update_dpp(
      __float_as_int(oldv), __float_as_int(v), CTRL, 0xF, 0xF, false));
}
template <int CTRL>
__device__ __forceinline__ int dpp_i(int v, int oldv) {
  return __builtin_amdgcn_update_dpp(oldv, v, CTRL, 0xF, 0xF, false);
}

template <int CTRL>
__device__ __forceinline__ void fps_combine2(float& val, int& idx) {
  const float tv = dpp_f<CTRL>(val, -1.0f);
  const int ti = dpp_i<CTRL>(idx, 0x7fffffff);
  const bool take = (tv > val) || (tv == val && ti < idx);
  val = take ? tv : val;
  idx = take ? ti : idx;
}

// ---------------- FPS: TWO blocks per batch (grid 32), paired via global exchange ----
// r16's deadlock: single slot per block -> writer overwrites tag s+1 with s+2
// before slow partner reads it; '==' poll spins forever. FIX: parity
// double-buffer gbuf[(b*2+h)*2 + (s&1)]. A slot written at step s (tag s+1)
// is only overwritten at s+2 (tag s+3), and reaching s+2 requires the partner
// to have consumed tag s+1 (it must publish s+2 first, which follows its own
// read of s+1) -> read-before-overwrite guaranteed, '==' stays exact.
// Each block owns 2048 points (8/thread in AGPRs). Per step: half-scan + DPP
// + intra-block resolve, then t0 release-stores (valbits<<32|idx<<11|tag) and
// all threads acquire-poll the partner slot; combine with global-index
// tie-break; fetch sp[bj]. Replay-safe: gbuf zeroed via hipMemsetAsync inside
// the graph; tags 1..1024 monotone within a run.
// Bit-exact vs numpy: contract(off) distances, same op order; half h owns
// global indices h*2048+t*8+j (ascending scan -> first-on-tie); cross-half
// combine compares global indices.
__global__ __launch_bounds__(256, 1) void fps_kernel(
    const float* __restrict__ xyz, float* __restrict__ newxyz,
    unsigned long long* __restrict__ gbuf) {
  const int b = blockIdx.x >> 1;
  const int h = blockIdx.x & 1;
  const int t = threadIdx.x;
  __shared__ float4 sp[N_];      // full batch coords for centroid fetch (64 KB)
  __shared__ float2 rec[2][4];   // [parity][wave] = (val, idxbits)
  __shared__ float cbuf[S_ * 3]; // selected centroids (h==0 only)
  const float* xb = xyz + (size_t)b * N_ * 3;
  for (int p = t; p < N_; p += 256) {
    sp[p] = make_float4(xb[p * 3 + 0], xb[p * 3 + 1], xb[p * 3 + 2], 0.0f);
  }
  // park this block's 2048 points (8/thread, consecutive) in AGPRs
  const int base = h * 2048 + t * 8;
  float ax[8], ay[8], az[8];
#pragma unroll
  for (int j = 0; j < 8; ++j) {
    const int p = base + j;
    const float x = xb[p * 3 + 0];
    const float y = xb[p * 3 + 1];
    const float z = xb[p * 3 + 2];
    asm volatile("v_accvgpr_write_b32 %0, %1" : "=a"(ax[j]) : "v"(x));
    asm volatile("v_accvgpr_write_b32 %0, %1" : "=a"(ay[j]) : "v"(y));
    asm volatile("v_accvgpr_write_b32 %0, %1" : "=a"(az[j]) : "v"(z));
  }
  float dist[8];
#pragma unroll
  for (int j = 0; j < 8; ++j) dist[j] = 1e10f;
  __syncthreads();
  float cx = xb[0], cy = xb[1], cz = xb[2];  // farthest init = point 0
  unsigned long long* myslots = &gbuf[(b * 2 + h) * 2];
  unsigned long long* pslots = &gbuf[(b * 2 + (1 - h)) * 2];
  for (int s = 0; s < S_; ++s) {
    if (h == 0 && t == 0) {
      cbuf[s * 3 + 0] = cx;
      cbuf[s * 3 + 1] = cy;
      cbuf[s * 3 + 2] = cz;
    }
    // coord fetch from AGPRs + independent distances
    float dd[8];
#pragma unroll
    for (int j = 0; j < 8; ++j) {
      float x, y, z;
      asm volatile("v_accvgpr_read_b32 %0, %1" : "=v"(x) : "a"(ax[j]));
      asm volatile("v_accvgpr_read_b32 %0, %1" : "=v"(y) : "a"(ay[j]));
      asm volatile("v_accvgpr_read_b32 %0, %1" : "=v"(z) : "a"(az[j]));
      dd[j] = sqdist3(x, y, z, cx, cy, cz);
    }
    __builtin_amdgcn_sched_barrier(0);
    // register-only min + local argmax (ascending global idx -> first on tie)
    float best = -1.0f;
    int bi = 0;
#pragma unroll
    for (int j = 0; j < 8; ++j) {
      const float nd = fminf(dist[j], dd[j]);
      dist[j] = nd;
      const bool take = nd > best;
      best = take ? nd : best;
      bi = take ? (base + j) : bi;
    }
    // DPP wave argmax (result complete in lane 63)
    fps_combine2<0x111>(best, bi);
    fps_combine2<0x112>(best, bi);
    fps_combine2<0x114>(best, bi);
    fps_combine2<0x118>(best, bi);
    fps_combine2<0x142>(best, bi);
    fps_combine2<0x143>(best, bi);
    const float wv = __int_as_float(__builtin_amdgcn_readlane(__float_as_int(best), 63));
    const int wi = __builtin_amdgcn_readlane(bi, 63);
    const int par = s & 1;
    if ((t & 63) == 0) {
      rec[par][t >> 6] = make_float2(wv, __int_as_float(wi));
    }
    __syncthreads();
    // intra-block resolve (redundant broadcast reads)
    float2 r0 = rec[par][0];
    float bv = r0.x;
    int bj = __float_as_int(r0.y);
#pragma unroll
    for (int w = 1; w < 4; ++w) {
      const float2 r = rec[par][w];
      const int iw = __float_as_int(r.y);
      const bool take = (r.x > bv) || (r.x == bv && iw < bj);
      bv = take ? r.x : bv;
      bj = take ? iw : bj;
    }
    // cross-block exchange: publish + poll partner (parity double-buffered)
    const unsigned tag = (unsigned)(s + 1);
    if (t == 0) {
      const unsigned long long myrec =
          ((unsigned long long)__float_as_uint(bv) << 32) |
          (unsigned long long)(((unsigned)bj << 11) | tag);
      __hip_atomic_store(&myslots[par], myrec, __ATOMIC_RELEASE,
                         __HIP_MEMORY_SCOPE_AGENT);
    }
    unsigned long long pr;
    do {
      pr = __hip_atomic_load(&pslots[par], __ATOMIC_ACQUIRE,
                             __HIP_MEMORY_SCOPE_AGENT);
    } while ((unsigned)(pr & 2047u) != tag);
    const float pv = __uint_as_float((unsigned)(pr >> 32));
    const int pj = (int)(((unsigned)pr & 0xFFFFFFFFu) >> 11);
    const bool takeP = (pv > bv) || (pv == bv && pj < bj);
    bj = takeP ? pj : bj;
    const float4 c = sp[bj];  // broadcast read
    cx = c.x; cy = c.y; cz = c.z;
  }
  if (h == 0) {
    __syncthreads();
    float* ob = newxyz + (size_t)b * S_ * 3;
    for (int i = t; i < S_ * 3; i += 256) ob[i] = cbuf[i];
  }
}

// ---------------- KNN: one wave per query, 4 queries/block (r7 proven) ----------------
__global__ __launch_bounds__(256, 2) void knn_kernel(
    const float* __restrict__ xyz, const float* __restrict__ newxyz,
    int* __restrict__ knn_idx) {
  const int bs0 = blockIdx.x * 4;
  const int b = bs0 >> 10;
  const int t = threadIdx.x;
  const int wave = t >> 6;
  const int lane = t & 63;
  __shared__ float sxx[N_];
  __shared__ float sxy[N_];
  __shared__ float sxz[N_];
  const float* xb = xyz + (size_t)b * N_ * 3;
  for (int p = t; p < N_; p += 256) {
    sxx[p] = xb[p * 3 + 0];
    sxy[p] = xb[p * 3 + 1];
    sxz[p] = xb[p * 3 + 2];
  }
  __syncthreads();
  const int bs = bs0 + wave;
  const float cx = newxyz[(size_t)bs * 3 + 0];
  const float cy = newxyz[(size_t)bs * 3 + 1];
  const float cz = newxyz[(size_t)bs * 3 + 2];
  float c2;
  {
#pragma clang fp contract(off)
    float s = cx * cx;
    s = s + cy * cy;
    s = s + cz * cz;
    c2 = s;
  }
  float d[64];
  float gval[8];
  int gidx[8];
#pragma unroll
  for (int g = 0; g < 8; ++g) {
    float gv = FLT_MAX;
    int gi = g * 8;
#pragma unroll
    for (int q = 0; q < 8; ++q) {
      const int j = g * 8 + q;
      const int p = j * 64 + lane;
      const float dd = knn_dist(c2, cx, cy, cz, sxx[p], sxy[p], sxz[p]);
      d[j] = dd;
      if (dd < gv) { gv = dd; gi = j; }
    }
    gval[g] = gv; gidx[g] = gi;
  }
  int* krow = knn_idx + (size_t)bs * K_;
  for (int it = 0; it < K_; ++it) {
    float best = gval[0];
    int bj = gidx[0];
#pragma unroll
    for (int g = 1; g < 8; ++g) {
      if (gval[g] < best || (gval[g] == best && gidx[g] < bj)) { best = gval[g]; bj = gidx[g]; }
    }
    int bidx = bj * 64 + lane;
#pragma unroll
    for (int off = 32; off >= 1; off >>= 1) {
      const float ov = __shfl_xor(best, off);
      const int oi = __shfl_xor(bidx, off);
      if (ov < best || (ov == best && oi < bidx)) { best = ov; bidx = oi; }
    }
    if (lane == 0) krow[it] = bidx;
    if (lane == (bidx & 63)) {
      const int jl = bidx >> 6;
      const int gg = jl >> 3;
      const int qq = jl & 7;
#pragma unroll
      for (int g = 0; g < 8; ++g) {
        if (g == gg) {
#pragma unroll
          for (int q = 0; q < 8; ++q) {
            d[g * 8 + q] = (q == qq) ? FLT_MAX : d[g * 8 + q];
          }
          float gv = FLT_MAX;
          int gi = g * 8;
#pragma unroll
          for (int q = 0; q < 8; ++q) {
            const int j = g * 8 + q;
            if (d[j] < gv) { gv = d[j]; gi = j; }
          }
          gval[g] = gv; gidx[g] = gi;
        }
      }
    }
  }
}

// ---------------- Register-blocked pass building blocks (r15-proven) ----------------

__device__ __forceinline__ void loadw0p(float* __restrict__ wbuf,
                                        const float* __restrict__ w0, int t) {
  for (int i = t; i < 68 * 64; i += 256) {
    const int c = i >> 6;
    wbuf[i] = (c < 67) ? w0[i] : 0.0f;
  }
}
__device__ __forceinline__ void loadw64(float* __restrict__ wbuf,
                                        const float* __restrict__ w, int t) {
  for (int i = t; i < 64 * 64; i += 256) wbuf[i] = w[i];
}
__device__ __forceinline__ void loadw_half(float* __restrict__ wbuf,
                                           const float* __restrict__ w2, int ofs, int t) {
  for (int i = t; i < 64 * 64; i += 256) {
    const int c = i >> 6, j = i & 63;
    wbuf[i] = w2[c * 128 + ofs + j];
  }
}

__device__ __forceinline__ void build4(float* __restrict__ act,
    const float* __restrict__ xyz, const float* __restrict__ points,
    const int* __restrict__ knn_idx, const float* __restrict__ newxyz,
    int bs0, int t) {
  const int b = bs0 >> 10;
  for (int i = t; i < QB * K_ * AST; i += 256) {
    const int q = i / AQ;
    const int rem = i - q * AQ;
    const int k = rem / AST;
    const int c = rem - k * AST;
    const int bs = bs0 + q;
    const int p = knn_idx[(size_t)bs * K_ + k];
    float v;
    if (c < 3) {
      v = xyz[((size_t)b * N_ + p) * 3 + c] - newxyz[(size_t)bs * 3 + c];
    } else if (c < 67) {
      v = points[((size_t)b * N_ + p) * 64 + (c - 3)];
    } else {
      v = 0.0f;
    }
    act[i] = v;
  }
}

template <int CQ>
__device__ __forceinline__ void mm4(const float* __restrict__ actq,
    const float* __restrict__ wbuf, const float* __restrict__ bias,
    float acc[4][8], int kslot, int g) {
#pragma unroll
  for (int j = 0; j < 8; ++j) {
    const float bj = bias[g * 8 + j];
#pragma unroll
    for (int i = 0; i < 4; ++i) acc[i][j] = bj;
  }
  for (int qd = 0; qd < CQ; ++qd) {
    float4 a[4];
#pragma unroll
    for (int i = 0; i < 4; ++i)
      a[i] = *(const float4*)&actq[(kslot * 4 + i) * AST + qd * 4];
#pragma unroll
    for (int cc = 0; cc < 4; ++cc) {
      const float4 wlo = *(const float4*)&wbuf[(qd * 4 + cc) * 64 + g * 8];
      const float4 whi = *(const float4*)&wbuf[(qd * 4 + cc) * 64 + g * 8 + 4];
#pragma unroll
      for (int i = 0; i < 4; ++i) {
        const float x = (cc == 0) ? a[i].x : (cc == 1) ? a[i].y
                        : (cc == 2) ? a[i].z : a[i].w;
        acc[i][0] += x * wlo.x;
        acc[i][1] += x * wlo.y;
        acc[i][2] += x * wlo.z;
        acc[i][3] += x * wlo.w;
        acc[i][4] += x * whi.x;
        acc[i][5] += x * whi.y;
        acc[i][6] += x * whi.z;
        acc[i][7] += x * whi.w;
      }
    }
  }
}

__device__ __forceinline__ void stats4(const float acc[4][8],
    float* __restrict__ psum, float* __restrict__ psq, int bs, int ofs, int r) {
  float s[8], ss[8];
#pragma unroll
  for (int j = 0; j < 8; ++j) {
    s[j] = ((acc[0][j] + acc[1][j]) + acc[2][j]) + acc[3][j];
    ss[j] = ((acc[0][j] * acc[0][j] + acc[1][j] * acc[1][j]) +
             acc[2][j] * acc[2][j]) + acc[3][j] * acc[3][j];
  }
#pragma unroll
  for (int m = 8; m <= 32; m <<= 1) {
#pragma unroll
    for (int j = 0; j < 8; ++j) {
      s[j] += __shfl_xor(s[j], m);
      ss[j] += __shfl_xor(ss[j], m);
    }
  }
  if (r < 8) {
#pragma unroll
    for (int j = 0; j < 8; ++j) {
      psum[(size_t)bs * 128 + ofs + r * 8 + j] = s[j];
      psq[(size_t)bs * 128 + ofs + r * 8 + j] = ss[j];
    }
  }
}

__device__ __forceinline__ void minmax4(const float acc[4][8],
    float* __restrict__ maxraw, float* __restrict__ minbuf, int bs, int ofs, int r) {
  float mx[8], mn[8];
#pragma unroll
  for (int j = 0; j < 8; ++j) {
    mx[j] = fmaxf(fmaxf(acc[0][j], acc[1][j]), fmaxf(acc[2][j], acc[3][j]));
    mn[j] = fminf(fminf(acc[0][j], acc[1][j]), fminf(acc[2][j], acc[3][j]));
  }
#pragma unroll
  for (int m = 8; m <= 32; m <<= 1) {
#pragma unroll
    for (int j = 0; j < 8; ++j) {
      mx[j] = fmaxf(mx[j], __shfl_xor(mx[j], m));
      mn[j] = fminf(mn[j], __shfl_xor(mn[j], m));
    }
  }
  if (r < 8) {
#pragma unroll
    for (int j = 0; j < 8; ++j) {
      maxraw[(size_t)bs * 128 + ofs + r * 8 + j] = mx[j];
      minbuf[(size_t)bs * 128 + ofs + r * 8 + j] = mn[j];
    }
  }
}

__device__ __forceinline__ void zstore4(const float acc[4][8],
    float* __restrict__ zrow, int kslot, int g) {
#pragma unroll
  for (int i = 0; i < 4; ++i) {
    const int base = (kslot * 4 + i) * 64 + g * 8;
    *(float4*)&zrow[base] = make_float4(acc[i][0], acc[i][1], acc[i][2], acc[i][3]);
    *(float4*)&zrow[base + 4] = make_float4(acc[i][4], acc[i][5], acc[i][6], acc[i][7]);
  }
}

// ======== FAST PATH: register-blocked 4-query passes, z-staged (r15-proven) ========

__global__ __launch_bounds__(256, 2) void passA4_kernel(
    const float* __restrict__ xyz, const float* __restrict__ points,
    const float* __restrict__ newxyz, const int* __restrict__ knn_idx,
    const float* __restrict__ w0, const float* __restrict__ b0,
    float* __restrict__ psum, float* __restrict__ psq, float* __restrict__ zbuf) {
  __shared__ __align__(16) float act[QB * AQ];
  __shared__ __align__(16) float wbuf[68 * 64];
  const int bs0 = blockIdx.x * QB, t = threadIdx.x;
  build4(act, xyz, points, knn_idx, newxyz, bs0, t);
  loadw0p(wbuf, w0, t);
  __syncthreads();
  const int q = t >> 6, r = t & 63, ks = r >> 3, g = r & 7;
  float acc[4][8];
  mm4<17>(act + q * AQ, wbuf, b0, acc, ks, g);
  stats4(acc, psum, psq, bs0 + q, 0, r);
  zstore4(acc, zbuf + (size_t)(bs0 + q) * 2048, ks, g);
}

__global__ __launch_bounds__(256, 2) void passB4_kernel(
    const float* __restrict__ w1, const float* __restrict__ b1,
    const float* __restrict__ scales, const float* __restrict__ shifts,
    float* __restrict__ psum, float* __restrict__ psq, float* __restrict__ zbuf) {
  __shared__ __align__(16) float act[QB * AQ];
  __shared__ __align__(16) float wbuf[64 * 64];
  const int bs0 = blockIdx.x * QB, t = threadIdx.x;
  const float* zb = zbuf + (size_t)bs0 * 2048;
  for (int i = t; i < QB * 2048; i += 256) {
    const int q2 = i >> 11;
    const int rem = i & 2047;
    const int k = rem >> 6;
    const int c = rem & 63;
    const float v = zb[i] * scales[c] + shifts[c];
    act[q2 * AQ + k * AST + c] = fmaxf(v, 0.0f);
  }
  loadw64(wbuf, w1, t);
  __syncthreads();
  const int q = t >> 6, r = t & 63, ks = r >> 3, g = r & 7;
  float acc[4][8];
  mm4<16>(act + q * AQ, wbuf, b1, acc, ks, g);
  stats4(acc, psum, psq, bs0 + q, 0, r);
  zstore4(acc, zbuf + (size_t)(bs0 + q) * 2048, ks, g);
}

__global__ __launch_bounds__(256, 2) void passC4_kernel(
    const float* __restrict__ w2, const float* __restrict__ b2,
    const float* __restrict__ scales1, const float* __restrict__ shifts1,
    float* __restrict__ psum, float* __restrict__ psq,
    float* __restrict__ maxraw, float* __restrict__ minbuf,
    const float* __restrict__ zbuf) {
  __shared__ __align__(16) float act[QB * AQ];
  __shared__ __align__(16) float wbuf[64 * 64];
  const int bs0 = blockIdx.x * QB, t = threadIdx.x;
  const float* zb = zbuf + (size_t)bs0 * 2048;
  for (int i = t; i < QB * 2048; i += 256) {
    const int q2 = i >> 11;
    const int rem = i & 2047;
    const int k = rem >> 6;
    const int c = rem & 63;
    const float v = zb[i] * scales1[c] + shifts1[c];
    act[q2 * AQ + k * AST + c] = fmaxf(v, 0.0f);
  }
  loadw_half(wbuf, w2, 0, t);
  __syncthreads();
  const int q = t >> 6, r = t & 63, ks = r >> 3, g = r & 7;
  float acc[4][8];
  mm4<16>(act + q * AQ, wbuf, b2, acc, ks, g);
  stats4(acc, psum, psq, bs0 + q, 0, r);
  minmax4(acc, maxraw, minbuf, bs0 + q, 0, r);
  __syncthreads();
  loadw_half(wbuf, w2, 64, t);
  __syncthreads();
  mm4<16>(act + q * AQ, wbuf, b2 + 64, acc, ks, g);
  stats4(acc, psum, psq, bs0 + q, 64, r);
  minmax4(acc, maxraw, minbuf, bs0 + q, 64, r);
}

// ======== FALLBACK PATH (r13-proven scalar recompute) ========

__device__ __forceinline__ void loadw(float* __restrict__ wbuf,
                                      const float* __restrict__ w, int n, int t) {
  for (int i = t; i < n; i += 256) wbuf[i] = w[i];
}

__device__ __forceinline__ void build_x0(float* __restrict__ act,
    const float* __restrict__ xyz, const float* __restrict__ points,
    const int* __restrict__ knn_idx, const float* __restrict__ newxyz,
    int bs, int t) {
  const int b = bs >> 10;
  const int* krow = knn_idx + (size_t)bs * K_;
  const float cx = newxyz[(size_t)bs * 3 + 0];
  const float cy = newxyz[(size_t)bs * 3 + 1];
  const float cz = newxyz[(size_t)bs * 3 + 2];
  for (int i = t; i < K_ * CIN0; i += 256) {
    const int k = i / CIN0;
    const int c = i - k * CIN0;
    const int p = krow[k];
    float v;
    if (c < 3) {
      v = xyz[((size_t)b * N_ + p) * 3 + c] - (c == 0 ? cx : (c == 1 ? cy : cz));
    } else {
      v = points[((size_t)b * N_ + p) * 64 + (c - 3)];
    }
    act[k * AST + c] = v;
  }
}

template <int CIN>
__device__ __forceinline__ void matmul64(const float* __restrict__ act,
    const float* __restrict__ wbuf, const float* __restrict__ bias,
    float* __restrict__ out, int t) {
  const int k = t >> 3;
  const int g = t & 7;
  float acc[8];
#pragma unroll
  for (int j = 0; j < 8; ++j) acc[j] = bias[g * 8 + j];
  for (int c = 0; c < CIN; ++c) {
    const float xv = act[k * AST + c];
    const float4 wa = *(const float4*)&wbuf[c * 64 + g * 8];
    const float4 wb = *(const float4*)&wbuf[c * 64 + g * 8 + 4];
    acc[0] += xv * wa.x; acc[1] += xv * wa.y;
    acc[2] += xv * wa.z; acc[3] += xv * wa.w;
    acc[4] += xv * wb.x; acc[5] += xv * wb.y;
    acc[6] += xv * wb.z; acc[7] += xv * wb.w;
  }
  *(float4*)&out[k * AST + g * 8] = make_float4(acc[0], acc[1], acc[2], acc[3]);
  *(float4*)&out[k * AST + g * 8 + 4] = make_float4(acc[4], acc[5], acc[6], acc[7]);
}

__device__ __forceinline__ void norm_relu64(float* __restrict__ act,
    const float* __restrict__ scale, const float* __restrict__ shift, int t) {
  for (int i = t; i < K_ * 64; i += 256) {
    const int k = i >> 6, c = i & 63;
    const float v = act[k * AST + c] * scale[c] + shift[c];
    act[k * AST + c] = fmaxf(v, 0.0f);
  }
}

__device__ __forceinline__ void stats64(const float* __restrict__ out,
    float* __restrict__ psum, float* __restrict__ psq, int bs, int ofs, int t) {
  if (t < 64) {
    float s = 0.f, q = 0.f;
    for (int k = 0; k < K_; ++k) {
      const float v = out[k * AST + t];
      s += v; q += v * v;
    }
    psum[(size_t)bs * 128 + ofs + t] = s;
    psq[(size_t)bs * 128 + ofs + t] = q;
  }
}

__device__ __forceinline__ void minmax64(const float* __restrict__ out,
    float* __restrict__ maxraw, float* __restrict__ minbuf, int bs, int ofs, int t) {
  if (t >= 64 && t < 128) {
    const int ch = t - 64;
    float mx = -FLT_MAX, mn = FLT_MAX;
    for (int k = 0; k < K_; ++k) {
      const float v = out[k * AST + ch];
      mx = fmaxf(mx, v); mn = fminf(mn, v);
    }
    maxraw[(size_t)bs * 128 + ofs + ch] = mx;
    minbuf[(size_t)bs * 128 + ofs + ch] = mn;
  }
}

__global__ __launch_bounds__(256) void passA_kernel(
    const float* __restrict__ xyz, const float* __restrict__ points,
    const float* __restrict__ newxyz, const int* __restrict__ knn_idx,
    const float* __restrict__ w0, const float* __restrict__ b0,
    float* __restrict__ psum, float* __restrict__ psq) {
  __shared__ __align__(16) float actA[K_ * AST];
  __shared__ __align__(16) float outB[K_ * AST];
  __shared__ __align__(16) float wbuf[CIN0 * 64];
  const int bs = blockIdx.x, t = threadIdx.x;
  build_x0(actA, xyz, points, knn_idx, newxyz, bs, t);
  loadw(wbuf, w0, CIN0 * 64, t);
  __syncthreads();
  matmul64<CIN0>(actA, wbuf, b0, outB, t);
  __syncthreads();
  stats64(outB, psum, psq, bs, 0, t);
}

__global__ __launch_bounds__(256) void passB_kernel(
    const float* __restrict__ xyz, const float* __restrict__ points,
    const float* __restrict__ newxyz, const int* __restrict__ knn_idx,
    const float* __restrict__ w0, const float* __restrict__ b0,
    const float* __restrict__ w1, const float* __restrict__ b1,
    const float* __restrict__ scales, const float* __restrict__ shifts,
    float* __restrict__ psum, float* __restrict__ psq) {
  __shared__ __align__(16) float actA[K_ * AST];
  __shared__ __align__(16) float outB[K_ * AST];
  __shared__ __align__(16) float wbuf[CIN0 * 64];
  const int bs = blockIdx.x, t = threadIdx.x;
  build_x0(actA, xyz, points, knn_idx, newxyz, bs, t);
  loadw(wbuf, w0, CIN0 * 64, t);
  __syncthreads();
  matmul64<CIN0>(actA, wbuf, b0, outB, t);
  __syncthreads();
  norm_relu64(outB, scales, shifts, t);
  loadw(wbuf, w1, 64 * 64, t);
  __syncthreads();
  matmul64<64>(outB, wbuf, b1, actA, t);
  __syncthreads();
  stats64(actA, psum, psq, bs, 0, t);
}

__global__ __launch_bounds__(256) void passC_kernel(
    const float* __restrict__ xyz, const float* __restrict__ points,
    const float* __restrict__ newxyz, const int* __restrict__ knn_idx,
    const float* __restrict__ w0, const float* __restrict__ b0,
    const float* __restrict__ w1, const float* __restrict__ b1,
    const float* __restrict__ w2, const float* __restrict__ b2,
    const float* __restrict__ scales, const float* __restrict__ shifts,
    float* __restrict__ psum, float* __restrict__ psq,
    float* __restrict__ maxraw, float* __restrict__ minbuf) {
  __shared__ __align__(16) float actA[K_ * AST];
  __shared__ __align__(16) float outB[K_ * AST];
  __shared__ __align__(16) float wbuf[CIN0 * 64];
  const int bs = blockIdx.x, t = threadIdx.x;
  build_x0(actA, xyz, points, knn_idx, newxyz, bs, t);
  loadw(wbuf, w0, CIN0 * 64, t);
  __syncthreads();
  matmul64<CIN0>(actA, wbuf, b0, outB, t);
  __syncthreads();
  norm_relu64(outB, scales, shifts, t);
  loadw(wbuf, w1, 64 * 64, t);
  __syncthreads();
  matmul64<64>(outB, wbuf, b1, actA, t);
  __syncthreads();
  norm_relu64(actA, scales + 128, shifts + 128, t);
  loadw_half(wbuf, w2, 0, t);
  __syncthreads();
  matmul64<64>(actA, wbuf, b2, outB, t);
  __syncthreads();
  stats64(outB, psum, psq, bs, 0, t);
  minmax64(outB, maxraw, minbuf, bs, 0, t);
  loadw_half(wbuf, w2, 64, t);
  __syncthreads();
  matmul64<64>(actA, wbuf, b2 + 64, outB, t);
  __syncthreads();
  stats64(outB, psum, psq, bs, 64, t);
  minmax64(outB, maxraw, minbuf, bs, 64, t);
}

// ---------------- BN finalize ----------------
__global__ __launch_bounds__(256) void finalize_kernel(
    const float* __restrict__ psum, const float* __restrict__ psq,
    const float* __restrict__ g, const float* __restrict__ be,
    float* __restrict__ scale, float* __restrict__ shift) {
  const int ch = blockIdx.x, t = threadIdx.x;
  __shared__ float ss[256];
  __shared__ float sq[256];
  float s = 0.f, q = 0.f;
  for (int p = t; p < NBS; p += 256) {
    s += psum[(size_t)p * 128 + ch];
    q += psq[(size_t)p * 128 + ch];
  }
  ss[t] = s; sq[t] = q;
  __syncthreads();
  for (int off = 128; off >= 1; off >>= 1) {
    if (t < off) { ss[t] += ss[t + off]; sq[t] += sq[t + off]; }
    __syncthreads();
  }
  if (t == 0) {
    const float invN = 1.0f / (float)(B_ * S_ * K_);
    const float mean = ss[0] * invN;
    const float var = sq[0] * invN - mean * mean;
    const float sc = g[ch] / sqrtf(var + 1e-5f);
    scale[ch] = sc;
    shift[ch] = be[ch] - mean * sc;
  }
}

// ---------------- Final ----------------
__global__ __launch_bounds__(256) void final_kernel(
    const float* __restrict__ minbuf, const float* __restrict__ scale,
    const float* __restrict__ shift, float* __restrict__ out) {
  const int i = blockIdx.x * 256 + threadIdx.x;  // < B*S*128
  const int ch = i & 127;
  const float sc = scale[ch], sh = shift[ch];
  const float mx = out[NEWXYZ_FLOATS + i];
  const float mn = minbuf[i];
  const float v = sc * (sc >= 0.f ? mx : mn) + sh;
  out[NEWXYZ_FLOATS + i] = fmaxf(v, 0.f);
}

// ---------------- host ----------------
extern "C" void kernel_launch(void* const* d_in, const int* in_sizes, int n_in,
                              void* d_out, int out_size, void* d_ws, size_t ws_size,
                              hipStream_t stream) {
  const float* xyz = (const float*)d_in[0];
  const float* points = (const float*)d_in[1];
  const float* w0 = (const float*)d_in[2];
  const float* b0 = (const float*)d_in[3];
  const float* g0 = (const float*)d_in[4];
  const float* be0 = (const float*)d_in[5];
  const float* w1 = (const float*)d_in[6];
  const float* b1 = (const float*)d_in[7];
  const float* g1 = (const float*)d_in[8];
  const float* be1 = (const float*)d_in[9];
  const float* w2 = (const float*)d_in[10];
  const float* b2 = (const float*)d_in[11];
  const float* g2 = (const float*)d_in[12];
  const float* be2 = (const float*)d_in[13];
  float* out = (float*)d_out;
  float* newxyz = out;
  float* maxraw = out + NEWXYZ_FLOATS;

  float* ws = (float*)d_ws;
  // layout: [gbuf 64 u64 = 128 floats][knn_idx][...]
  unsigned long long* gbuf = (unsigned long long*)ws;
  const size_t NEED_FAST =
      (size_t)(128 + 524288 + 16384 * 2048 + 2 * NBS * 128 + 768 + NBS * 128) * 4;

  hipMemsetAsync(gbuf, 0, 64 * sizeof(unsigned long long), stream);
  fps_kernel<<<B_ * 2, 256, 0, stream>>>(xyz, newxyz, gbuf);

  if (ws_size >= NEED_FAST) {
    int* knn_idx = (int*)(ws + 128);
    float* zbuf = ws + 128 + 524288;
    float* psum = zbuf + (size_t)16384 * 2048;
    float* psq = psum + (size_t)NBS * 128;
    float* scales = psq + (size_t)NBS * 128;
    float* shifts = scales + 384;
    float* minbuf = shifts + 384;
    knn_kernel<<<NBS / 4, 256, 0, stream>>>(xyz, newxyz, knn_idx);
    passA4_kernel<<<NBS / QB, 256, 0, stream>>>(xyz, points, newxyz, knn_idx, w0, b0,
                                                psum, psq, zbuf);
    finalize_kernel<<<64, 256, 0, stream>>>(psum, psq, g0, be0, scales, shifts);
    passB4_kernel<<<NBS / QB, 256, 0, stream>>>(w1, b1, scales, shifts, psum, psq, zbuf);
    finalize_kernel<<<64, 256, 0, stream>>>(psum, psq, g1, be1, scales + 128, shifts + 128);
    passC4_kernel<<<NBS / QB, 256, 0, stream>>>(w2, b2, scales + 128, shifts + 128,
                                                psum, psq, maxraw, minbuf, zbuf);
    finalize_kernel<<<128, 256, 0, stream>>>(psum, psq, g2, be2, scales + 256, shifts + 256);
    final_kernel<<<(B_ * S_ * 128) / 256, 256, 0, stream>>>(minbuf, scales + 256,
                                                            shifts + 256, out);
  } else {
    int* knn_idx = (int*)(ws + 128);
    float* psum = ws + 128 + 524288;
    float* psq = psum + (size_t)NBS * 128;
    float* scales = psq + (size_t)NBS * 128;
    float* shifts = scales + 384;
    float* minbuf = shifts + 384;
    knn_kernel<<<NBS / 4, 256, 0, stream>>>(xyz, newxyz, knn_idx);
    passA_kernel<<<NBS, 256, 0, stream>>>(xyz, points, newxyz, knn_idx, w0, b0, psum, psq);
    finalize_kernel<<<64, 256, 0, stream>>>(psum, psq, g0, be0, scales, shifts);
    passB_kernel<<<NBS, 256, 0, stream>>>(xyz, points, newxyz, knn_idx, w0, b0, w1, b1,
                                          scales, shifts, psum, psq);
    finalize_kernel<<<64, 256, 0, stream>>>(psum, psq, g1, be1, scales + 128, shifts + 128);
    passC_kernel<<<NBS, 256, 0, stream>>>(xyz, points, newxyz, knn_idx, w0, b0, w1, b1, w2, b2,
                                          scales, shifts, psum, psq, maxraw, minbuf);
    finalize_kernel<<<128, 256, 0, stream>>>(psum, psq, g2, be2, scales + 256, shifts + 256);
    final_kernel<<<(B_ * S_ * 128) / 256, 256, 0, stream>>>(minbuf, scales + 256,
                                                            shifts + 256, out);
  }
}

// Round 18
// 2162.972 us; speedup vs baseline: 1.4517x; 1.4517x over previous
//
#include <hip/hip_runtime.h>
#include <float.h>
#include <math.h>

// Problem constants
#define B_ 16
#define N_ 4096
#define S_ 1024
#define K_ 32
#define CIN0 67              // 3 + 64
#define NBS (B_ * S_)        // 16384
#define NEWXYZ_FLOATS (B_ * S_ * 3)  // 49152
#define AST 68               // LDS activation row stride
#define AQ (K_ * AST)        // 2176 floats per query
#define QB 4                 // queries per pass-block (wave = query)

// ---------------- helpers ----------------

__device__ __forceinline__ float sqdist3(float x, float y, float z,
                                         float cx, float cy, float cz) {
#pragma clang fp contract(off)
  float dx = x - cx, dy = y - cy, dz = z - cz;
  float s = dx * dx;
  s = s + dy * dy;
  s = s + dz * dz;
  return s;
}

__device__ __forceinline__ float knn_dist(float c2, float cx, float cy, float cz,
                                          float x, float y, float z) {
#pragma clang fp contract(off)
  float dot = cx * x; dot = dot + cy * y; dot = dot + cz * z;
  float x2 = x * x;   x2 = x2 + y * y;   x2 = x2 + z * z;
  float d = c2 - 2.0f * dot;
  d = d + x2;
  return d;
}

// ---- DPP cross-lane (gfx9: row_shr:N=0x110|N, row_bcast15=0x142, row_bcast31=0x143) ----
template <int CTRL>
__device__ __forceinline__ float dpp_f(float v, float oldv) {
  return __int_as_float(__builtin_amdgcn_update_dpp(
      __float_as_int(oldv), __float_as_int(v), CTRL, 0xF, 0xF, false));
}
template <int CTRL>
__device__ __forceinline__ int dpp_i(int v, int oldv) {
  return __builtin_amdgcn_update_dpp(oldv, v, CTRL, 0xF, 0xF, false);
}

template <int CTRL>
__device__ __forceinline__ void fps_combine2(float& val, int& idx) {
  const float tv = dpp_f<CTRL>(val, -1.0f);
  const int ti = dpp_i<CTRL>(idx, 0x7fffffff);
  const bool take = (tv > val) || (tv == val && ti < idx);
  val = take ? tv : val;
  idx = take ? ti : idx;
}

// ---------------- FPS: TWO batches per 512-thread block (grid 8) ----------------
// r17 lesson: any per-step cross-CU sync is fatal (2.15x slower). Instead,
// hide latency with intra-CU TLP: waves 0-3 process batch 2i, waves 4-7 batch
// 2i+1, fully independent state (own LDS planes, cbuf, rec, centroid regs),
// coupled only by the (symmetric-work) joint barrier. Each SIMD holds 2 waves
// from INDEPENDENT serial chains -> one fills the other's stalls (fps was
// 46% VALU-busy on active CUs = latency-bound at occupancy 1).
// Per-group structure identical to the r14/r15-proven fps (AGPR-parked coords,
// DPP argmax, LDS cbuf, end flush). Bit-exact vs numpy: contract(off)
// distances, same op order, first-index tie-break (thread owns consecutive
// points tt*16+j, ascending scan).
__global__ __launch_bounds__(512, 1) void fps_kernel(
    const float* __restrict__ xyz, float* __restrict__ newxyz) {
  const int grp = threadIdx.x >> 8;         // 0 or 1
  const int tt = threadIdx.x & 255;         // thread within group
  const int b = blockIdx.x * 2 + grp;       // batch
  __shared__ float spx[2][N_];              // 2 x 16 KB
  __shared__ float spy[2][N_];
  __shared__ float spz[2][N_];
  __shared__ float cbuf[2][S_ * 3];         // 2 x 12 KB
  __shared__ float2 rec[2][2][4];           // [grp][parity][wave-in-group]
  const float* xb = xyz + (size_t)b * N_ * 3;
  for (int p = tt; p < N_; p += 256) {
    spx[grp][p] = xb[p * 3 + 0];
    spy[grp][p] = xb[p * 3 + 1];
    spz[grp][p] = xb[p * 3 + 2];
  }
  // park this thread's 16 consecutive points in AGPRs
  float ax[16], ay[16], az[16];
#pragma unroll
  for (int j = 0; j < 16; ++j) {
    const int p = tt * 16 + j;
    const float x = xb[p * 3 + 0];
    const float y = xb[p * 3 + 1];
    const float z = xb[p * 3 + 2];
    asm volatile("v_accvgpr_write_b32 %0, %1" : "=a"(ax[j]) : "v"(x));
    asm volatile("v_accvgpr_write_b32 %0, %1" : "=a"(ay[j]) : "v"(y));
    asm volatile("v_accvgpr_write_b32 %0, %1" : "=a"(az[j]) : "v"(z));
  }
  float dist[16];
#pragma unroll
  for (int j = 0; j < 16; ++j) dist[j] = 1e10f;
  __syncthreads();
  float cx = xb[0], cy = xb[1], cz = xb[2];  // farthest init = point 0
  for (int s = 0; s < S_; ++s) {
    if (tt == 0) {
      cbuf[grp][s * 3 + 0] = cx;
      cbuf[grp][s * 3 + 1] = cy;
      cbuf[grp][s * 3 + 2] = cz;
    }
    // coord fetch from AGPRs (VALU-rate) + independent distances
    float dd[16];
#pragma unroll
    for (int j = 0; j < 16; ++j) {
      float x, y, z;
      asm volatile("v_accvgpr_read_b32 %0, %1" : "=v"(x) : "a"(ax[j]));
      asm volatile("v_accvgpr_read_b32 %0, %1" : "=v"(y) : "a"(ay[j]));
      asm volatile("v_accvgpr_read_b32 %0, %1" : "=v"(z) : "a"(az[j]));
      dd[j] = sqdist3(x, y, z, cx, cy, cz);
    }
    __builtin_amdgcn_sched_barrier(0);
    // register-only min + local argmax (ascending idx -> first on tie)
    float best = -1.0f;
    int bi = 0;
#pragma unroll
    for (int j = 0; j < 16; ++j) {
      const float nd = fminf(dist[j], dd[j]);
      dist[j] = nd;
      const bool take = nd > best;
      best = take ? nd : best;
      bi = take ? (tt * 16 + j) : bi;
    }
    // DPP wave argmax (hardware wave = 64 lanes, all same group)
    fps_combine2<0x111>(best, bi);
    fps_combine2<0x112>(best, bi);
    fps_combine2<0x114>(best, bi);
    fps_combine2<0x118>(best, bi);
    fps_combine2<0x142>(best, bi);
    fps_combine2<0x143>(best, bi);
    const float wv = __int_as_float(__builtin_amdgcn_readlane(__float_as_int(best), 63));
    const int wi = __builtin_amdgcn_readlane(bi, 63);
    const int par = s & 1;
    if ((tt & 63) == 0) {
      rec[grp][par][tt >> 6] = make_float2(wv, __int_as_float(wi));
    }
    __syncthreads();
    // resolve this group's 4 wave candidates redundantly (broadcast reads)
    float2 r0 = rec[grp][par][0];
    float bv = r0.x;
    int bj = __float_as_int(r0.y);
#pragma unroll
    for (int w = 1; w < 4; ++w) {
      const float2 r = rec[grp][par][w];
      const int iw = __float_as_int(r.y);
      const bool take = (r.x > bv) || (r.x == bv && iw < bj);
      bv = take ? r.x : bv;
      bj = take ? iw : bj;
    }
    cx = spx[grp][bj];  // broadcast reads
    cy = spy[grp][bj];
    cz = spz[grp][bj];
  }
  // coalesced flush of this group's 1024 centroids
  __syncthreads();
  float* ob = newxyz + (size_t)b * S_ * 3;
  for (int i = tt; i < S_ * 3; i += 256) ob[i] = cbuf[grp][i];
}

// ---------------- KNN: one wave per query, 4 queries/block (r7 proven) ----------------
__global__ __launch_bounds__(256, 2) void knn_kernel(
    const float* __restrict__ xyz, const float* __restrict__ newxyz,
    int* __restrict__ knn_idx) {
  const int bs0 = blockIdx.x * 4;
  const int b = bs0 >> 10;
  const int t = threadIdx.x;
  const int wave = t >> 6;
  const int lane = t & 63;
  __shared__ float sxx[N_];
  __shared__ float sxy[N_];
  __shared__ float sxz[N_];
  const float* xb = xyz + (size_t)b * N_ * 3;
  for (int p = t; p < N_; p += 256) {
    sxx[p] = xb[p * 3 + 0];
    sxy[p] = xb[p * 3 + 1];
    sxz[p] = xb[p * 3 + 2];
  }
  __syncthreads();
  const int bs = bs0 + wave;
  const float cx = newxyz[(size_t)bs * 3 + 0];
  const float cy = newxyz[(size_t)bs * 3 + 1];
  const float cz = newxyz[(size_t)bs * 3 + 2];
  float c2;
  {
#pragma clang fp contract(off)
    float s = cx * cx;
    s = s + cy * cy;
    s = s + cz * cz;
    c2 = s;
  }
  float d[64];
  float gval[8];
  int gidx[8];
#pragma unroll
  for (int g = 0; g < 8; ++g) {
    float gv = FLT_MAX;
    int gi = g * 8;
#pragma unroll
    for (int q = 0; q < 8; ++q) {
      const int j = g * 8 + q;
      const int p = j * 64 + lane;
      const float dd = knn_dist(c2, cx, cy, cz, sxx[p], sxy[p], sxz[p]);
      d[j] = dd;
      if (dd < gv) { gv = dd; gi = j; }
    }
    gval[g] = gv; gidx[g] = gi;
  }
  int* krow = knn_idx + (size_t)bs * K_;
  for (int it = 0; it < K_; ++it) {
    float best = gval[0];
    int bj = gidx[0];
#pragma unroll
    for (int g = 1; g < 8; ++g) {
      if (gval[g] < best || (gval[g] == best && gidx[g] < bj)) { best = gval[g]; bj = gidx[g]; }
    }
    int bidx = bj * 64 + lane;
#pragma unroll
    for (int off = 32; off >= 1; off >>= 1) {
      const float ov = __shfl_xor(best, off);
      const int oi = __shfl_xor(bidx, off);
      if (ov < best || (ov == best && oi < bidx)) { best = ov; bidx = oi; }
    }
    if (lane == 0) krow[it] = bidx;
    if (lane == (bidx & 63)) {
      const int jl = bidx >> 6;
      const int gg = jl >> 3;
      const int qq = jl & 7;
#pragma unroll
      for (int g = 0; g < 8; ++g) {
        if (g == gg) {
#pragma unroll
          for (int q = 0; q < 8; ++q) {
            d[g * 8 + q] = (q == qq) ? FLT_MAX : d[g * 8 + q];
          }
          float gv = FLT_MAX;
          int gi = g * 8;
#pragma unroll
          for (int q = 0; q < 8; ++q) {
            const int j = g * 8 + q;
            if (d[j] < gv) { gv = d[j]; gi = j; }
          }
          gval[g] = gv; gidx[g] = gi;
        }
      }
    }
  }
}

// ---------------- Register-blocked pass building blocks (r15-proven) ----------------

__device__ __forceinline__ void loadw0p(float* __restrict__ wbuf,
                                        const float* __restrict__ w0, int t) {
  for (int i = t; i < 68 * 64; i += 256) {
    const int c = i >> 6;
    wbuf[i] = (c < 67) ? w0[i] : 0.0f;
  }
}
__device__ __forceinline__ void loadw64(float* __restrict__ wbuf,
                                        const float* __restrict__ w, int t) {
  for (int i = t; i < 64 * 64; i += 256) wbuf[i] = w[i];
}
__device__ __forceinline__ void loadw_half(float* __restrict__ wbuf,
                                           const float* __restrict__ w2, int ofs, int t) {
  for (int i = t; i < 64 * 64; i += 256) {
    const int c = i >> 6, j = i & 63;
    wbuf[i] = w2[c * 128 + ofs + j];
  }
}

__device__ __forceinline__ void build4(float* __restrict__ act,
    const float* __restrict__ xyz, const float* __restrict__ points,
    const int* __restrict__ knn_idx, const float* __restrict__ newxyz,
    int bs0, int t) {
  const int b = bs0 >> 10;
  for (int i = t; i < QB * K_ * AST; i += 256) {
    const int q = i / AQ;
    const int rem = i - q * AQ;
    const int k = rem / AST;
    const int c = rem - k * AST;
    const int bs = bs0 + q;
    const int p = knn_idx[(size_t)bs * K_ + k];
    float v;
    if (c < 3) {
      v = xyz[((size_t)b * N_ + p) * 3 + c] - newxyz[(size_t)bs * 3 + c];
    } else if (c < 67) {
      v = points[((size_t)b * N_ + p) * 64 + (c - 3)];
    } else {
      v = 0.0f;
    }
    act[i] = v;
  }
}

template <int CQ>
__device__ __forceinline__ void mm4(const float* __restrict__ actq,
    const float* __restrict__ wbuf, const float* __restrict__ bias,
    float acc[4][8], int kslot, int g) {
#pragma unroll
  for (int j = 0; j < 8; ++j) {
    const float bj = bias[g * 8 + j];
#pragma unroll
    for (int i = 0; i < 4; ++i) acc[i][j] = bj;
  }
  for (int qd = 0; qd < CQ; ++qd) {
    float4 a[4];
#pragma unroll
    for (int i = 0; i < 4; ++i)
      a[i] = *(const float4*)&actq[(kslot * 4 + i) * AST + qd * 4];
#pragma unroll
    for (int cc = 0; cc < 4; ++cc) {
      const float4 wlo = *(const float4*)&wbuf[(qd * 4 + cc) * 64 + g * 8];
      const float4 whi = *(const float4*)&wbuf[(qd * 4 + cc) * 64 + g * 8 + 4];
#pragma unroll
      for (int i = 0; i < 4; ++i) {
        const float x = (cc == 0) ? a[i].x : (cc == 1) ? a[i].y
                        : (cc == 2) ? a[i].z : a[i].w;
        acc[i][0] += x * wlo.x;
        acc[i][1] += x * wlo.y;
        acc[i][2] += x * wlo.z;
        acc[i][3] += x * wlo.w;
        acc[i][4] += x * whi.x;
        acc[i][5] += x * whi.y;
        acc[i][6] += x * whi.z;
        acc[i][7] += x * whi.w;
      }
    }
  }
}

__device__ __forceinline__ void stats4(const float acc[4][8],
    float* __restrict__ psum, float* __restrict__ psq, int bs, int ofs, int r) {
  float s[8], ss[8];
#pragma unroll
  for (int j = 0; j < 8; ++j) {
    s[j] = ((acc[0][j] + acc[1][j]) + acc[2][j]) + acc[3][j];
    ss[j] = ((acc[0][j] * acc[0][j] + acc[1][j] * acc[1][j]) +
             acc[2][j] * acc[2][j]) + acc[3][j] * acc[3][j];
  }
#pragma unroll
  for (int m = 8; m <= 32; m <<= 1) {
#pragma unroll
    for (int j = 0; j < 8; ++j) {
      s[j] += __shfl_xor(s[j], m);
      ss[j] += __shfl_xor(ss[j], m);
    }
  }
  if (r < 8) {
#pragma unroll
    for (int j = 0; j < 8; ++j) {
      psum[(size_t)bs * 128 + ofs + r * 8 + j] = s[j];
      psq[(size_t)bs * 128 + ofs + r * 8 + j] = ss[j];
    }
  }
}

__device__ __forceinline__ void minmax4(const float acc[4][8],
    float* __restrict__ maxraw, float* __restrict__ minbuf, int bs, int ofs, int r) {
  float mx[8], mn[8];
#pragma unroll
  for (int j = 0; j < 8; ++j) {
    mx[j] = fmaxf(fmaxf(acc[0][j], acc[1][j]), fmaxf(acc[2][j], acc[3][j]));
    mn[j] = fminf(fminf(acc[0][j], acc[1][j]), fminf(acc[2][j], acc[3][j]));
  }
#pragma unroll
  for (int m = 8; m <= 32; m <<= 1) {
#pragma unroll
    for (int j = 0; j < 8; ++j) {
      mx[j] = fmaxf(mx[j], __shfl_xor(mx[j], m));
      mn[j] = fminf(mn[j], __shfl_xor(mn[j], m));
    }
  }
  if (r < 8) {
#pragma unroll
    for (int j = 0; j < 8; ++j) {
      maxraw[(size_t)bs * 128 + ofs + r * 8 + j] = mx[j];
      minbuf[(size_t)bs * 128 + ofs + r * 8 + j] = mn[j];
    }
  }
}

__device__ __forceinline__ void zstore4(const float acc[4][8],
    float* __restrict__ zrow, int kslot, int g) {
#pragma unroll
  for (int i = 0; i < 4; ++i) {
    const int base = (kslot * 4 + i) * 64 + g * 8;
    *(float4*)&zrow[base] = make_float4(acc[i][0], acc[i][1], acc[i][2], acc[i][3]);
    *(float4*)&zrow[base + 4] = make_float4(acc[i][4], acc[i][5], acc[i][6], acc[i][7]);
  }
}

// ======== FAST PATH: register-blocked 4-query passes, z-staged (r15-proven) ========

__global__ __launch_bounds__(256, 2) void passA4_kernel(
    const float* __restrict__ xyz, const float* __restrict__ points,
    const float* __restrict__ newxyz, const int* __restrict__ knn_idx,
    const float* __restrict__ w0, const float* __restrict__ b0,
    float* __restrict__ psum, float* __restrict__ psq, float* __restrict__ zbuf) {
  __shared__ __align__(16) float act[QB * AQ];
  __shared__ __align__(16) float wbuf[68 * 64];
  const int bs0 = blockIdx.x * QB, t = threadIdx.x;
  build4(act, xyz, points, knn_idx, newxyz, bs0, t);
  loadw0p(wbuf, w0, t);
  __syncthreads();
  const int q = t >> 6, r = t & 63, ks = r >> 3, g = r & 7;
  float acc[4][8];
  mm4<17>(act + q * AQ, wbuf, b0, acc, ks, g);
  stats4(acc, psum, psq, bs0 + q, 0, r);
  zstore4(acc, zbuf + (size_t)(bs0 + q) * 2048, ks, g);
}

__global__ __launch_bounds__(256, 2) void passB4_kernel(
    const float* __restrict__ w1, const float* __restrict__ b1,
    const float* __restrict__ scales, const float* __restrict__ shifts,
    float* __restrict__ psum, float* __restrict__ psq, float* __restrict__ zbuf) {
  __shared__ __align__(16) float act[QB * AQ];
  __shared__ __align__(16) float wbuf[64 * 64];
  const int bs0 = blockIdx.x * QB, t = threadIdx.x;
  const float* zb = zbuf + (size_t)bs0 * 2048;
  for (int i = t; i < QB * 2048; i += 256) {
    const int q2 = i >> 11;
    const int rem = i & 2047;
    const int k = rem >> 6;
    const int c = rem & 63;
    const float v = zb[i] * scales[c] + shifts[c];
    act[q2 * AQ + k * AST + c] = fmaxf(v, 0.0f);
  }
  loadw64(wbuf, w1, t);
  __syncthreads();
  const int q = t >> 6, r = t & 63, ks = r >> 3, g = r & 7;
  float acc[4][8];
  mm4<16>(act + q * AQ, wbuf, b1, acc, ks, g);
  stats4(acc, psum, psq, bs0 + q, 0, r);
  zstore4(acc, zbuf + (size_t)(bs0 + q) * 2048, ks, g);
}

__global__ __launch_bounds__(256, 2) void passC4_kernel(
    const float* __restrict__ w2, const float* __restrict__ b2,
    const float* __restrict__ scales1, const float* __restrict__ shifts1,
    float* __restrict__ psum, float* __restrict__ psq,
    float* __restrict__ maxraw, float* __restrict__ minbuf,
    const float* __restrict__ zbuf) {
  __shared__ __align__(16) float act[QB * AQ];
  __shared__ __align__(16) float wbuf[64 * 64];
  const int bs0 = blockIdx.x * QB, t = threadIdx.x;
  const float* zb = zbuf + (size_t)bs0 * 2048;
  for (int i = t; i < QB * 2048; i += 256) {
    const int q2 = i >> 11;
    const int rem = i & 2047;
    const int k = rem >> 6;
    const int c = rem & 63;
    const float v = zb[i] * scales1[c] + shifts1[c];
    act[q2 * AQ + k * AST + c] = fmaxf(v, 0.0f);
  }
  loadw_half(wbuf, w2, 0, t);
  __syncthreads();
  const int q = t >> 6, r = t & 63, ks = r >> 3, g = r & 7;
  float acc[4][8];
  mm4<16>(act + q * AQ, wbuf, b2, acc, ks, g);
  stats4(acc, psum, psq, bs0 + q, 0, r);
  minmax4(acc, maxraw, minbuf, bs0 + q, 0, r);
  __syncthreads();
  loadw_half(wbuf, w2, 64, t);
  __syncthreads();
  mm4<16>(act + q * AQ, wbuf, b2 + 64, acc, ks, g);
  stats4(acc, psum, psq, bs0 + q, 64, r);
  minmax4(acc, maxraw, minbuf, bs0 + q, 64, r);
}

// ======== FALLBACK PATH (r13-proven scalar recompute) ========

__device__ __forceinline__ void loadw(float* __restrict__ wbuf,
                                      const float* __restrict__ w, int n, int t) {
  for (int i = t; i < n; i += 256) wbuf[i] = w[i];
}

__device__ __forceinline__ void build_x0(float* __restrict__ act,
    const float* __restrict__ xyz, const float* __restrict__ points,
    const int* __restrict__ knn_idx, const float* __restrict__ newxyz,
    int bs, int t) {
  const int b = bs >> 10;
  const int* krow = knn_idx + (size_t)bs * K_;
  const float cx = newxyz[(size_t)bs * 3 + 0];
  const float cy = newxyz[(size_t)bs * 3 + 1];
  const float cz = newxyz[(size_t)bs * 3 + 2];
  for (int i = t; i < K_ * CIN0; i += 256) {
    const int k = i / CIN0;
    const int c = i - k * CIN0;
    const int p = krow[k];
    float v;
    if (c < 3) {
      v = xyz[((size_t)b * N_ + p) * 3 + c] - (c == 0 ? cx : (c == 1 ? cy : cz));
    } else {
      v = points[((size_t)b * N_ + p) * 64 + (c - 3)];
    }
    act[k * AST + c] = v;
  }
}

template <int CIN>
__device__ __forceinline__ void matmul64(const float* __restrict__ act,
    const float* __restrict__ wbuf, const float* __restrict__ bias,
    float* __restrict__ out, int t) {
  const int k = t >> 3;
  const int g = t & 7;
  float acc[8];
#pragma unroll
  for (int j = 0; j < 8; ++j) acc[j] = bias[g * 8 + j];
  for (int c = 0; c < CIN; ++c) {
    const float xv = act[k * AST + c];
    const float4 wa = *(const float4*)&wbuf[c * 64 + g * 8];
    const float4 wb = *(const float4*)&wbuf[c * 64 + g * 8 + 4];
    acc[0] += xv * wa.x; acc[1] += xv * wa.y;
    acc[2] += xv * wa.z; acc[3] += xv * wa.w;
    acc[4] += xv * wb.x; acc[5] += xv * wb.y;
    acc[6] += xv * wb.z; acc[7] += xv * wb.w;
  }
  *(float4*)&out[k * AST + g * 8] = make_float4(acc[0], acc[1], acc[2], acc[3]);
  *(float4*)&out[k * AST + g * 8 + 4] = make_float4(acc[4], acc[5], acc[6], acc[7]);
}

__device__ __forceinline__ void norm_relu64(float* __restrict__ act,
    const float* __restrict__ scale, const float* __restrict__ shift, int t) {
  for (int i = t; i < K_ * 64; i += 256) {
    const int k = i >> 6, c = i & 63;
    const float v = act[k * AST + c] * scale[c] + shift[c];
    act[k * AST + c] = fmaxf(v, 0.0f);
  }
}

__device__ __forceinline__ void stats64(const float* __restrict__ out,
    float* __restrict__ psum, float* __restrict__ psq, int bs, int ofs, int t) {
  if (t < 64) {
    float s = 0.f, q = 0.f;
    for (int k = 0; k < K_; ++k) {
      const float v = out[k * AST + t];
      s += v; q += v * v;
    }
    psum[(size_t)bs * 128 + ofs + t] = s;
    psq[(size_t)bs * 128 + ofs + t] = q;
  }
}

__device__ __forceinline__ void minmax64(const float* __restrict__ out,
    float* __restrict__ maxraw, float* __restrict__ minbuf, int bs, int ofs, int t) {
  if (t >= 64 && t < 128) {
    const int ch = t - 64;
    float mx = -FLT_MAX, mn = FLT_MAX;
    for (int k = 0; k < K_; ++k) {
      const float v = out[k * AST + ch];
      mx = fmaxf(mx, v); mn = fminf(mn, v);
    }
    maxraw[(size_t)bs * 128 + ofs + ch] = mx;
    minbuf[(size_t)bs * 128 + ofs + ch] = mn;
  }
}

__global__ __launch_bounds__(256) void passA_kernel(
    const float* __restrict__ xyz, const float* __restrict__ points,
    const float* __restrict__ newxyz, const int* __restrict__ knn_idx,
    const float* __restrict__ w0, const float* __restrict__ b0,
    float* __restrict__ psum, float* __restrict__ psq) {
  __shared__ __align__(16) float actA[K_ * AST];
  __shared__ __align__(16) float outB[K_ * AST];
  __shared__ __align__(16) float wbuf[CIN0 * 64];
  const int bs = blockIdx.x, t = threadIdx.x;
  build_x0(actA, xyz, points, knn_idx, newxyz, bs, t);
  loadw(wbuf, w0, CIN0 * 64, t);
  __syncthreads();
  matmul64<CIN0>(actA, wbuf, b0, outB, t);
  __syncthreads();
  stats64(outB, psum, psq, bs, 0, t);
}

__global__ __launch_bounds__(256) void passB_kernel(
    const float* __restrict__ xyz, const float* __restrict__ points,
    const float* __restrict__ newxyz, const int* __restrict__ knn_idx,
    const float* __restrict__ w0, const float* __restrict__ b0,
    const float* __restrict__ w1, const float* __restrict__ b1,
    const float* __restrict__ scales, const float* __restrict__ shifts,
    float* __restrict__ psum, float* __restrict__ psq) {
  __shared__ __align__(16) float actA[K_ * AST];
  __shared__ __align__(16) float outB[K_ * AST];
  __shared__ __align__(16) float wbuf[CIN0 * 64];
  const int bs = blockIdx.x, t = threadIdx.x;
  build_x0(actA, xyz, points, knn_idx, newxyz, bs, t);
  loadw(wbuf, w0, CIN0 * 64, t);
  __syncthreads();
  matmul64<CIN0>(actA, wbuf, b0, outB, t);
  __syncthreads();
  norm_relu64(outB, scales, shifts, t);
  loadw(wbuf, w1, 64 * 64, t);
  __syncthreads();
  matmul64<64>(outB, wbuf, b1, actA, t);
  __syncthreads();
  stats64(actA, psum, psq, bs, 0, t);
}

__global__ __launch_bounds__(256) void passC_kernel(
    const float* __restrict__ xyz, const float* __restrict__ points,
    const float* __restrict__ newxyz, const int* __restrict__ knn_idx,
    const float* __restrict__ w0, const float* __restrict__ b0,
    const float* __restrict__ w1, const float* __restrict__ b1,
    const float* __restrict__ w2, const float* __restrict__ b2,
    const float* __restrict__ scales, const float* __restrict__ shifts,
    float* __restrict__ psum, float* __restrict__ psq,
    float* __restrict__ maxraw, float* __restrict__ minbuf) {
  __shared__ __align__(16) float actA[K_ * AST];
  __shared__ __align__(16) float outB[K_ * AST];
  __shared__ __align__(16) float wbuf[CIN0 * 64];
  const int bs = blockIdx.x, t = threadIdx.x;
  build_x0(actA, xyz, points, knn_idx, newxyz, bs, t);
  loadw(wbuf, w0, CIN0 * 64, t);
  __syncthreads();
  matmul64<CIN0>(actA, wbuf, b0, outB, t);
  __syncthreads();
  norm_relu64(outB, scales, shifts, t);
  loadw(wbuf, w1, 64 * 64, t);
  __syncthreads();
  matmul64<64>(outB, wbuf, b1, actA, t);
  __syncthreads();
  norm_relu64(actA, scales + 128, shifts + 128, t);
  loadw_half(wbuf, w2, 0, t);
  __syncthreads();
  matmul64<64>(actA, wbuf, b2, outB, t);
  __syncthreads();
  stats64(outB, psum, psq, bs, 0, t);
  minmax64(outB, maxraw, minbuf, bs, 0, t);
  loadw_half(wbuf, w2, 64, t);
  __syncthreads();
  matmul64<64>(actA, wbuf, b2 + 64, outB, t);
  __syncthreads();
  stats64(outB, psum, psq, bs, 64, t);
  minmax64(outB, maxraw, minbuf, bs, 64, t);
}

// ---------------- BN finalize ----------------
__global__ __launch_bounds__(256) void finalize_kernel(
    const float* __restrict__ psum, const float* __restrict__ psq,
    const float* __restrict__ g, const float* __restrict__ be,
    float* __restrict__ scale, float* __restrict__ shift) {
  const int ch = blockIdx.x, t = threadIdx.x;
  __shared__ float ss[256];
  __shared__ float sq[256];
  float s = 0.f, q = 0.f;
  for (int p = t; p < NBS; p += 256) {
    s += psum[(size_t)p * 128 + ch];
    q += psq[(size_t)p * 128 + ch];
  }
  ss[t] = s; sq[t] = q;
  __syncthreads();
  for (int off = 128; off >= 1; off >>= 1) {
    if (t < off) { ss[t] += ss[t + off]; sq[t] += sq[t + off]; }
    __syncthreads();
  }
  if (t == 0) {
    const float invN = 1.0f / (float)(B_ * S_ * K_);
    const float mean = ss[0] * invN;
    const float var = sq[0] * invN - mean * mean;
    const float sc = g[ch] / sqrtf(var + 1e-5f);
    scale[ch] = sc;
    shift[ch] = be[ch] - mean * sc;
  }
}

// ---------------- Final ----------------
__global__ __launch_bounds__(256) void final_kernel(
    const float* __restrict__ minbuf, const float* __restrict__ scale,
    const float* __restrict__ shift, float* __restrict__ out) {
  const int i = blockIdx.x * 256 + threadIdx.x;  // < B*S*128
  const int ch = i & 127;
  const float sc = scale[ch], sh = shift[ch];
  const float mx = out[NEWXYZ_FLOATS + i];
  const float mn = minbuf[i];
  const float v = sc * (sc >= 0.f ? mx : mn) + sh;
  out[NEWXYZ_FLOATS + i] = fmaxf(v, 0.f);
}

// ---------------- host ----------------
extern "C" void kernel_launch(void* const* d_in, const int* in_sizes, int n_in,
                              void* d_out, int out_size, void* d_ws, size_t ws_size,
                              hipStream_t stream) {
  const float* xyz = (const float*)d_in[0];
  const float* points = (const float*)d_in[1];
  const float* w0 = (const float*)d_in[2];
  const float* b0 = (const float*)d_in[3];
  const float* g0 = (const float*)d_in[4];
  const float* be0 = (const float*)d_in[5];
  const float* w1 = (const float*)d_in[6];
  const float* b1 = (const float*)d_in[7];
  const float* g1 = (const float*)d_in[8];
  const float* be1 = (const float*)d_in[9];
  const float* w2 = (const float*)d_in[10];
  const float* b2 = (const float*)d_in[11];
  const float* g2 = (const float*)d_in[12];
  const float* be2 = (const float*)d_in[13];
  float* out = (float*)d_out;
  float* newxyz = out;
  float* maxraw = out + NEWXYZ_FLOATS;

  float* ws = (float*)d_ws;
  const size_t NEED_FAST =
      (size_t)(524288 + 16384 * 2048 + 2 * NBS * 128 + 768 + NBS * 128) * 4;

  fps_kernel<<<B_ / 2, 512, 0, stream>>>(xyz, newxyz);

  if (ws_size >= NEED_FAST) {
    int* knn_idx = (int*)ws;
    float* zbuf = ws + 524288;
    float* psum = zbuf + (size_t)16384 * 2048;
    float* psq = psum + (size_t)NBS * 128;
    float* scales = psq + (size_t)NBS * 128;
    float* shifts = scales + 384;
    float* minbuf = shifts + 384;
    knn_kernel<<<NBS / 4, 256, 0, stream>>>(xyz, newxyz, knn_idx);
    passA4_kernel<<<NBS / QB, 256, 0, stream>>>(xyz, points, newxyz, knn_idx, w0, b0,
                                                psum, psq, zbuf);
    finalize_kernel<<<64, 256, 0, stream>>>(psum, psq, g0, be0, scales, shifts);
    passB4_kernel<<<NBS / QB, 256, 0, stream>>>(w1, b1, scales, shifts, psum, psq, zbuf);
    finalize_kernel<<<64, 256, 0, stream>>>(psum, psq, g1, be1, scales + 128, shifts + 128);
    passC4_kernel<<<NBS / QB, 256, 0, stream>>>(w2, b2, scales + 128, shifts + 128,
                                                psum, psq, maxraw, minbuf, zbuf);
    finalize_kernel<<<128, 256, 0, stream>>>(psum, psq, g2, be2, scales + 256, shifts + 256);
    final_kernel<<<(B_ * S_ * 128) / 256, 256, 0, stream>>>(minbuf, scales + 256,
                                                            shifts + 256, out);
  } else {
    int* knn_idx = (int*)ws;
    float* psum = ws + 524288;
    float* psq = psum + (size_t)NBS * 128;
    float* scales = psq + (size_t)NBS * 128;
    float* shifts = scales + 384;
    float* minbuf = shifts + 384;
    knn_kernel<<<NBS / 4, 256, 0, stream>>>(xyz, newxyz, knn_idx);
    passA_kernel<<<NBS, 256, 0, stream>>>(xyz, points, newxyz, knn_idx, w0, b0, psum, psq);
    finalize_kernel<<<64, 256, 0, stream>>>(psum, psq, g0, be0, scales, shifts);
    passB_kernel<<<NBS, 256, 0, stream>>>(xyz, points, newxyz, knn_idx, w0, b0, w1, b1,
                                          scales, shifts, psum, psq);
    finalize_kernel<<<64, 256, 0, stream>>>(psum, psq, g1, be1, scales + 128, shifts + 128);
    passC_kernel<<<NBS, 256, 0, stream>>>(xyz, points, newxyz, knn_idx, w0, b0, w1, b1, w2, b2,
                                          scales, shifts, psum, psq, maxraw, minbuf);
    finalize_kernel<<<128, 256, 0, stream>>>(psum, psq, g2, be2, scales + 256, shifts + 256);
    final_kernel<<<(B_ * S_ * 128) / 256, 256, 0, stream>>>(minbuf, scales + 256,
                                                            shifts + 256, out);
  }
}

// Round 19
// 1864.788 us; speedup vs baseline: 1.6839x; 1.1599x over previous
//
#include <hip/hip_runtime.h>
#include <float.h>
#include <math.h>

// Problem constants
#define B_ 16
#define N_ 4096
#define S_ 1024
#define K_ 32
#define CIN0 67              // 3 + 64
#define NBS (B_ * S_)        // 16384
#define NEWXYZ_FLOATS (B_ * S_ * 3)  // 49152
#define AST 68               // LDS activation row stride
#define AQ (K_ * AST)        // 2176 floats per query
#define QB 4                 // queries per pass-block (wave = query)

// ---------------- helpers ----------------

__device__ __forceinline__ float sqdist3(float x, float y, float z,
                                         float cx, float cy, float cz) {
#pragma clang fp contract(off)
  float dx = x - cx, dy = y - cy, dz = z - cz;
  float s = dx * dx;
  s = s + dy * dy;
  s = s + dz * dz;
  return s;
}

__device__ __forceinline__ float knn_dist(float c2, float cx, float cy, float cz,
                                          float x, float y, float z) {
#pragma clang fp contract(off)
  float dot = cx * x; dot = dot + cy * y; dot = dot + cz * z;
  float x2 = x * x;   x2 = x2 + y * y;   x2 = x2 + z * z;
  float d = c2 - 2.0f * dot;
  d = d + x2;
  return d;
}

// ---- DPP cross-lane (gfx9: row_shr:N=0x110|N, row_bcast15=0x142, row_bcast31=0x143) ----
template <int CTRL>
__device__ __forceinline__ float dpp_f(float v, float oldv) {
  return __int_as_float(__builtin_amdgcn_update_dpp(
      __float_as_int(oldv), __float_as_int(v), CTRL, 0xF, 0xF, false));
}
template <int CTRL>
__device__ __forceinline__ int dpp_i(int v, int oldv) {
  return __builtin_amdgcn_update_dpp(oldv, v, CTRL, 0xF, 0xF, false);
}

template <int CTRL>
__device__ __forceinline__ void fps_combine2(float& val, int& idx) {
  const float tv = dpp_f<CTRL>(val, -1.0f);
  const int ti = dpp_i<CTRL>(idx, 0x7fffffff);
  const bool take = (tv > val) || (tv == val && ti < idx);
  val = take ? tv : val;
  idx = take ? ti : idx;
}

// ---------------- FPS: r14-proven (1090us) ----------------
__global__ __launch_bounds__(256, 1) void fps_kernel(
    const float* __restrict__ xyz, float* __restrict__ newxyz) {
  const int b = blockIdx.x;
  const int t = threadIdx.x;
  __shared__ float4 sp[N_];
  __shared__ float2 rec[2][4];
  __shared__ float cbuf[S_ * 3];
  const float* xb = xyz + (size_t)b * N_ * 3;
  for (int p = t; p < N_; p += 256) {
    sp[p] = make_float4(xb[p * 3 + 0], xb[p * 3 + 1], xb[p * 3 + 2], 0.0f);
  }
  float ax[16], ay[16], az[16];
#pragma unroll
  for (int j = 0; j < 16; ++j) {
    const int p = t * 16 + j;
    const float x = xb[p * 3 + 0];
    const float y = xb[p * 3 + 1];
    const float z = xb[p * 3 + 2];
    asm volatile("v_accvgpr_write_b32 %0, %1" : "=a"(ax[j]) : "v"(x));
    asm volatile("v_accvgpr_write_b32 %0, %1" : "=a"(ay[j]) : "v"(y));
    asm volatile("v_accvgpr_write_b32 %0, %1" : "=a"(az[j]) : "v"(z));
  }
  float dist[16];
#pragma unroll
  for (int j = 0; j < 16; ++j) dist[j] = 1e10f;
  __syncthreads();
  float cx = xb[0], cy = xb[1], cz = xb[2];
  for (int s = 0; s < S_; ++s) {
    if (t == 0) {
      cbuf[s * 3 + 0] = cx;
      cbuf[s * 3 + 1] = cy;
      cbuf[s * 3 + 2] = cz;
    }
    float dd[16];
#pragma unroll
    for (int j = 0; j < 16; ++j) {
      float x, y, z;
      asm volatile("v_accvgpr_read_b32 %0, %1" : "=v"(x) : "a"(ax[j]));
      asm volatile("v_accvgpr_read_b32 %0, %1" : "=v"(y) : "a"(ay[j]));
      asm volatile("v_accvgpr_read_b32 %0, %1" : "=v"(z) : "a"(az[j]));
      dd[j] = sqdist3(x, y, z, cx, cy, cz);
    }
    __builtin_amdgcn_sched_barrier(0);
    float best = -1.0f;
    int bi = 0;
#pragma unroll
    for (int j = 0; j < 16; ++j) {
      const float nd = fminf(dist[j], dd[j]);
      dist[j] = nd;
      const bool take = nd > best;
      best = take ? nd : best;
      bi = take ? (t * 16 + j) : bi;
    }
    fps_combine2<0x111>(best, bi);
    fps_combine2<0x112>(best, bi);
    fps_combine2<0x114>(best, bi);
    fps_combine2<0x118>(best, bi);
    fps_combine2<0x142>(best, bi);
    fps_combine2<0x143>(best, bi);
    const float wv = __int_as_float(__builtin_amdgcn_readlane(__float_as_int(best), 63));
    const int wi = __builtin_amdgcn_readlane(bi, 63);
    const int par = s & 1;
    if ((t & 63) == 0) {
      rec[par][t >> 6] = make_float2(wv, __int_as_float(wi));
    }
    __syncthreads();
    float2 r0 = rec[par][0];
    float bv = r0.x;
    int bj = __float_as_int(r0.y);
#pragma unroll
    for (int w = 1; w < 4; ++w) {
      const float2 r = rec[par][w];
      const int iw = __float_as_int(r.y);
      const bool take = (r.x > bv) || (r.x == bv && iw < bj);
      bv = take ? r.x : bv;
      bj = take ? iw : bj;
    }
    const float4 c = sp[bj];
    cx = c.x; cy = c.y; cz = c.z;
  }
  __syncthreads();
  float* ob = newxyz + (size_t)b * S_ * 3;
  for (int i = t; i < S_ * 3; i += 256) ob[i] = cbuf[i];
}

// ---------------- KNN: one wave per query, 4 queries/block (r7 proven) ----------------
__global__ __launch_bounds__(256, 2) void knn_kernel(
    const float* __restrict__ xyz, const float* __restrict__ newxyz,
    int* __restrict__ knn_idx) {
  const int bs0 = blockIdx.x * 4;
  const int b = bs0 >> 10;
  const int t = threadIdx.x;
  const int wave = t >> 6;
  const int lane = t & 63;
  __shared__ float sxx[N_];
  __shared__ float sxy[N_];
  __shared__ float sxz[N_];
  const float* xb = xyz + (size_t)b * N_ * 3;
  for (int p = t; p < N_; p += 256) {
    sxx[p] = xb[p * 3 + 0];
    sxy[p] = xb[p * 3 + 1];
    sxz[p] = xb[p * 3 + 2];
  }
  __syncthreads();
  const int bs = bs0 + wave;
  const float cx = newxyz[(size_t)bs * 3 + 0];
  const float cy = newxyz[(size_t)bs * 3 + 1];
  const float cz = newxyz[(size_t)bs * 3 + 2];
  float c2;
  {
#pragma clang fp contract(off)
    float s = cx * cx;
    s = s + cy * cy;
    s = s + cz * cz;
    c2 = s;
  }
  float d[64];
  float gval[8];
  int gidx[8];
#pragma unroll
  for (int g = 0; g < 8; ++g) {
    float gv = FLT_MAX;
    int gi = g * 8;
#pragma unroll
    for (int q = 0; q < 8; ++q) {
      const int j = g * 8 + q;
      const int p = j * 64 + lane;
      const float dd = knn_dist(c2, cx, cy, cz, sxx[p], sxy[p], sxz[p]);
      d[j] = dd;
      if (dd < gv) { gv = dd; gi = j; }
    }
    gval[g] = gv; gidx[g] = gi;
  }
  int* krow = knn_idx + (size_t)bs * K_;
  for (int it = 0; it < K_; ++it) {
    float best = gval[0];
    int bj = gidx[0];
#pragma unroll
    for (int g = 1; g < 8; ++g) {
      if (gval[g] < best || (gval[g] == best && gidx[g] < bj)) { best = gval[g]; bj = gidx[g]; }
    }
    int bidx = bj * 64 + lane;
#pragma unroll
    for (int off = 32; off >= 1; off >>= 1) {
      const float ov = __shfl_xor(best, off);
      const int oi = __shfl_xor(bidx, off);
      if (ov < best || (ov == best && oi < bidx)) { best = ov; bidx = oi; }
    }
    if (lane == 0) krow[it] = bidx;
    if (lane == (bidx & 63)) {
      const int jl = bidx >> 6;
      const int gg = jl >> 3;
      const int qq = jl & 7;
#pragma unroll
      for (int g = 0; g < 8; ++g) {
        if (g == gg) {
#pragma unroll
          for (int q = 0; q < 8; ++q) {
            d[g * 8 + q] = (q == qq) ? FLT_MAX : d[g * 8 + q];
          }
          float gv = FLT_MAX;
          int gi = g * 8;
#pragma unroll
          for (int q = 0; q < 8; ++q) {
            const int j = g * 8 + q;
            if (d[j] < gv) { gv = d[j]; gi = j; }
          }
          gval[g] = gv; gidx[g] = gi;
        }
      }
    }
  }
}

// ---------------- Register-blocked pass building blocks (r15-proven) ----------------

__device__ __forceinline__ void loadw0p(float* __restrict__ wbuf,
                                        const float* __restrict__ w0, int t) {
  for (int i = t; i < 68 * 64; i += 256) {
    const int c = i >> 6;
    wbuf[i] = (c < 67) ? w0[i] : 0.0f;
  }
}
__device__ __forceinline__ void loadw64(float* __restrict__ wbuf,
                                        const float* __restrict__ w, int t) {
  for (int i = t; i < 64 * 64; i += 256) wbuf[i] = w[i];
}
__device__ __forceinline__ void loadw_half(float* __restrict__ wbuf,
                                           const float* __restrict__ w2, int ofs, int t) {
  for (int i = t; i < 64 * 64; i += 256) {
    const int c = i >> 6, j = i & 63;
    wbuf[i] = w2[c * 128 + ofs + j];
  }
}

__device__ __forceinline__ void build4(float* __restrict__ act,
    const float* __restrict__ xyz, const float* __restrict__ points,
    const int* __restrict__ knn_idx, const float* __restrict__ newxyz,
    int bs0, int t) {
  const int b = bs0 >> 10;
  for (int i = t; i < QB * K_ * AST; i += 256) {
    const int q = i / AQ;
    const int rem = i - q * AQ;
    const int k = rem / AST;
    const int c = rem - k * AST;
    const int bs = bs0 + q;
    const int p = knn_idx[(size_t)bs * K_ + k];
    float v;
    if (c < 3) {
      v = xyz[((size_t)b * N_ + p) * 3 + c] - newxyz[(size_t)bs * 3 + c];
    } else if (c < 67) {
      v = points[((size_t)b * N_ + p) * 64 + (c - 3)];
    } else {
      v = 0.0f;
    }
    act[i] = v;
  }
}

template <int CQ>
__device__ __forceinline__ void mm4(const float* __restrict__ actq,
    const float* __restrict__ wbuf, const float* __restrict__ bias,
    float acc[4][8], int kslot, int g) {
#pragma unroll
  for (int j = 0; j < 8; ++j) {
    const float bj = bias[g * 8 + j];
#pragma unroll
    for (int i = 0; i < 4; ++i) acc[i][j] = bj;
  }
  for (int qd = 0; qd < CQ; ++qd) {
    float4 a[4];
#pragma unroll
    for (int i = 0; i < 4; ++i)
      a[i] = *(const float4*)&actq[(kslot * 4 + i) * AST + qd * 4];
#pragma unroll
    for (int cc = 0; cc < 4; ++cc) {
      const float4 wlo = *(const float4*)&wbuf[(qd * 4 + cc) * 64 + g * 8];
      const float4 whi = *(const float4*)&wbuf[(qd * 4 + cc) * 64 + g * 8 + 4];
#pragma unroll
      for (int i = 0; i < 4; ++i) {
        const float x = (cc == 0) ? a[i].x : (cc == 1) ? a[i].y
                        : (cc == 2) ? a[i].z : a[i].w;
        acc[i][0] += x * wlo.x;
        acc[i][1] += x * wlo.y;
        acc[i][2] += x * wlo.z;
        acc[i][3] += x * wlo.w;
        acc[i][4] += x * whi.x;
        acc[i][5] += x * whi.y;
        acc[i][6] += x * whi.z;
        acc[i][7] += x * whi.w;
      }
    }
  }
}

__device__ __forceinline__ void stats4(const float acc[4][8],
    float* __restrict__ psum, float* __restrict__ psq, int bs, int ofs, int r) {
  float s[8], ss[8];
#pragma unroll
  for (int j = 0; j < 8; ++j) {
    s[j] = ((acc[0][j] + acc[1][j]) + acc[2][j]) + acc[3][j];
    ss[j] = ((acc[0][j] * acc[0][j] + acc[1][j] * acc[1][j]) +
             acc[2][j] * acc[2][j]) + acc[3][j] * acc[3][j];
  }
#pragma unroll
  for (int m = 8; m <= 32; m <<= 1) {
#pragma unroll
    for (int j = 0; j < 8; ++j) {
      s[j] += __shfl_xor(s[j], m);
      ss[j] += __shfl_xor(ss[j], m);
    }
  }
  if (r < 8) {
#pragma unroll
    for (int j = 0; j < 8; ++j) {
      psum[(size_t)bs * 128 + ofs + r * 8 + j] = s[j];
      psq[(size_t)bs * 128 + ofs + r * 8 + j] = ss[j];
    }
  }
}

__device__ __forceinline__ void minmax4(const float acc[4][8],
    float* __restrict__ maxraw, float* __restrict__ minbuf, int bs, int ofs, int r) {
  float mx[8], mn[8];
#pragma unroll
  for (int j = 0; j < 8; ++j) {
    mx[j] = fmaxf(fmaxf(acc[0][j], acc[1][j]), fmaxf(acc[2][j], acc[3][j]));
    mn[j] = fminf(fminf(acc[0][j], acc[1][j]), fminf(acc[2][j], acc[3][j]));
  }
#pragma unroll
  for (int m = 8; m <= 32; m <<= 1) {
#pragma unroll
    for (int j = 0; j < 8; ++j) {
      mx[j] = fmaxf(mx[j], __shfl_xor(mx[j], m));
      mn[j] = fminf(mn[j], __shfl_xor(mn[j], m));
    }
  }
  if (r < 8) {
#pragma unroll
    for (int j = 0; j < 8; ++j) {
      maxraw[(size_t)bs * 128 + ofs + r * 8 + j] = mx[j];
      minbuf[(size_t)bs * 128 + ofs + r * 8 + j] = mn[j];
    }
  }
}

__device__ __forceinline__ void zstore4(const float acc[4][8],
    float* __restrict__ zrow, int kslot, int g) {
#pragma unroll
  for (int i = 0; i < 4; ++i) {
    const int base = (kslot * 4 + i) * 64 + g * 8;
    *(float4*)&zrow[base] = make_float4(acc[i][0], acc[i][1], acc[i][2], acc[i][3]);
    *(float4*)&zrow[base + 4] = make_float4(acc[i][4], acc[i][5], acc[i][6], acc[i][7]);
  }
}

// ======== FAST PATH: register-blocked 4-query passes, z-staged ========

__global__ __launch_bounds__(256, 2) void passA4_kernel(
    const float* __restrict__ xyz, const float* __restrict__ points,
    const float* __restrict__ newxyz, const int* __restrict__ knn_idx,
    const float* __restrict__ w0, const float* __restrict__ b0,
    float* __restrict__ psum, float* __restrict__ psq, float* __restrict__ zbuf) {
  __shared__ __align__(16) float act[QB * AQ];
  __shared__ __align__(16) float wbuf[68 * 64];
  const int bs0 = blockIdx.x * QB, t = threadIdx.x;
  build4(act, xyz, points, knn_idx, newxyz, bs0, t);
  loadw0p(wbuf, w0, t);
  __syncthreads();
  const int q = t >> 6, r = t & 63, ks = r >> 3, g = r & 7;
  float acc[4][8];
  mm4<17>(act + q * AQ, wbuf, b0, acc, ks, g);
  stats4(acc, psum, psq, bs0 + q, 0, r);
  zstore4(acc, zbuf + (size_t)(bs0 + q) * 2048, ks, g);
}

__global__ __launch_bounds__(256, 2) void passB4_kernel(
    const float* __restrict__ w1, const float* __restrict__ b1,
    const float* __restrict__ scales, const float* __restrict__ shifts,
    float* __restrict__ psum, float* __restrict__ psq, float* __restrict__ zbuf) {
  __shared__ __align__(16) float act[QB * AQ];
  __shared__ __align__(16) float wbuf[64 * 64];
  const int bs0 = blockIdx.x * QB, t = threadIdx.x;
  const float* zb = zbuf + (size_t)bs0 * 2048;
  for (int i = t; i < QB * 2048; i += 256) {
    const int q2 = i >> 11;
    const int rem = i & 2047;
    const int k = rem >> 6;
    const int c = rem & 63;
    const float v = zb[i] * scales[c] + shifts[c];
    act[q2 * AQ + k * AST + c] = fmaxf(v, 0.0f);
  }
  loadw64(wbuf, w1, t);
  __syncthreads();
  const int q = t >> 6, r = t & 63, ks = r >> 3, g = r & 7;
  float acc[4][8];
  mm4<16>(act + q * AQ, wbuf, b1, acc, ks, g);
  stats4(acc, psum, psq, bs0 + q, 0, r);
  zstore4(acc, zbuf + (size_t)(bs0 + q) * 2048, ks, g);
}

__global__ __launch_bounds__(256, 2) void passC4_kernel(
    const float* __restrict__ w2, const float* __restrict__ b2,
    const float* __restrict__ scales1, const float* __restrict__ shifts1,
    float* __restrict__ psum, float* __restrict__ psq,
    float* __restrict__ maxraw, float* __restrict__ minbuf,
    const float* __restrict__ zbuf) {
  __shared__ __align__(16) float act[QB * AQ];
  __shared__ __align__(16) float wbuf[64 * 64];
  const int bs0 = blockIdx.x * QB, t = threadIdx.x;
  const float* zb = zbuf + (size_t)bs0 * 2048;
  for (int i = t; i < QB * 2048; i += 256) {
    const int q2 = i >> 11;
    const int rem = i & 2047;
    const int k = rem >> 6;
    const int c = rem & 63;
    const float v = zb[i] * scales1[c] + shifts1[c];
    act[q2 * AQ + k * AST + c] = fmaxf(v, 0.0f);
  }
  loadw_half(wbuf, w2, 0, t);
  __syncthreads();
  const int q = t >> 6, r = t & 63, ks = r >> 3, g = r & 7;
  float acc[4][8];
  mm4<16>(act + q * AQ, wbuf, b2, acc, ks, g);
  stats4(acc, psum, psq, bs0 + q, 0, r);
  minmax4(acc, maxraw, minbuf, bs0 + q, 0, r);
  __syncthreads();
  loadw_half(wbuf, w2, 64, t);
  __syncthreads();
  mm4<16>(act + q * AQ, wbuf, b2 + 64, acc, ks, g);
  stats4(acc, psum, psq, bs0 + q, 64, r);
  minmax4(acc, maxraw, minbuf, bs0 + q, 64, r);
}

// ======== FALLBACK PATH (r13-proven scalar recompute) ========

__device__ __forceinline__ void loadw(float* __restrict__ wbuf,
                                      const float* __restrict__ w, int n, int t) {
  for (int i = t; i < n; i += 256) wbuf[i] = w[i];
}

__device__ __forceinline__ void build_x0(float* __restrict__ act,
    const float* __restrict__ xyz, const float* __restrict__ points,
    const int* __restrict__ knn_idx, const float* __restrict__ newxyz,
    int bs, int t) {
  const int b = bs >> 10;
  const int* krow = knn_idx + (size_t)bs * K_;
  const float cx = newxyz[(size_t)bs * 3 + 0];
  const float cy = newxyz[(size_t)bs * 3 + 1];
  const float cz = newxyz[(size_t)bs * 3 + 2];
  for (int i = t; i < K_ * CIN0; i += 256) {
    const int k = i / CIN0;
    const int c = i - k * CIN0;
    const int p = krow[k];
    float v;
    if (c < 3) {
      v = xyz[((size_t)b * N_ + p) * 3 + c] - (c == 0 ? cx : (c == 1 ? cy : cz));
    } else {
      v = points[((size_t)b * N_ + p) * 64 + (c - 3)];
    }
    act[k * AST + c] = v;
  }
}

template <int CIN>
__device__ __forceinline__ void matmul64(const float* __restrict__ act,
    const float* __restrict__ wbuf, const float* __restrict__ bias,
    float* __restrict__ out, int t) {
  const int k = t >> 3;
  const int g = t & 7;
  float acc[8];
#pragma unroll
  for (int j = 0; j < 8; ++j) acc[j] = bias[g * 8 + j];
  for (int c = 0; c < CIN; ++c) {
    const float xv = act[k * AST + c];
    const float4 wa = *(const float4*)&wbuf[c * 64 + g * 8];
    const float4 wb = *(const float4*)&wbuf[c * 64 + g * 8 + 4];
    acc[0] += xv * wa.x; acc[1] += xv * wa.y;
    acc[2] += xv * wa.z; acc[3] += xv * wa.w;
    acc[4] += xv * wb.x; acc[5] += xv * wb.y;
    acc[6] += xv * wb.z; acc[7] += xv * wb.w;
  }
  *(float4*)&out[k * AST + g * 8] = make_float4(acc[0], acc[1], acc[2], acc[3]);
  *(float4*)&out[k * AST + g * 8 + 4] = make_float4(acc[4], acc[5], acc[6], acc[7]);
}

__device__ __forceinline__ void norm_relu64(float* __restrict__ act,
    const float* __restrict__ scale, const float* __restrict__ shift, int t) {
  for (int i = t; i < K_ * 64; i += 256) {
    const int k = i >> 6, c = i & 63;
    const float v = act[k * AST + c] * scale[c] + shift[c];
    act[k * AST + c] = fmaxf(v, 0.0f);
  }
}

__device__ __forceinline__ void stats64(const float* __restrict__ out,
    float* __restrict__ psum, float* __restrict__ psq, int bs, int ofs, int t) {
  if (t < 64) {
    float s = 0.f, q = 0.f;
    for (int k = 0; k < K_; ++k) {
      const float v = out[k * AST + t];
      s += v; q += v * v;
    }
    psum[(size_t)bs * 128 + ofs + t] = s;
    psq[(size_t)bs * 128 + ofs + t] = q;
  }
}

__device__ __forceinline__ void minmax64(const float* __restrict__ out,
    float* __restrict__ maxraw, float* __restrict__ minbuf, int bs, int ofs, int t) {
  if (t >= 64 && t < 128) {
    const int ch = t - 64;
    float mx = -FLT_MAX, mn = FLT_MAX;
    for (int k = 0; k < K_; ++k) {
      const float v = out[k * AST + ch];
      mx = fmaxf(mx, v); mn = fminf(mn, v);
    }
    maxraw[(size_t)bs * 128 + ofs + ch] = mx;
    minbuf[(size_t)bs * 128 + ofs + ch] = mn;
  }
}

__global__ __launch_bounds__(256) void passA_kernel(
    const float* __restrict__ xyz, const float* __restrict__ points,
    const float* __restrict__ newxyz, const int* __restrict__ knn_idx,
    const float* __restrict__ w0, const float* __restrict__ b0,
    float* __restrict__ psum, float* __restrict__ psq) {
  __shared__ __align__(16) float actA[K_ * AST];
  __shared__ __align__(16) float outB[K_ * AST];
  __shared__ __align__(16) float wbuf[CIN0 * 64];
  const int bs = blockIdx.x, t = threadIdx.x;
  build_x0(actA, xyz, points, knn_idx, newxyz, bs, t);
  loadw(wbuf, w0, CIN0 * 64, t);
  __syncthreads();
  matmul64<CIN0>(actA, wbuf, b0, outB, t);
  __syncthreads();
  stats64(outB, psum, psq, bs, 0, t);
}

__global__ __launch_bounds__(256) void passB_kernel(
    const float* __restrict__ xyz, const float* __restrict__ points,
    const float* __restrict__ newxyz, const int* __restrict__ knn_idx,
    const float* __restrict__ w0, const float* __restrict__ b0,
    const float* __restrict__ w1, const float* __restrict__ b1,
    const float* __restrict__ scales, const float* __restrict__ shifts,
    float* __restrict__ psum, float* __restrict__ psq) {
  __shared__ __align__(16) float actA[K_ * AST];
  __shared__ __align__(16) float outB[K_ * AST];
  __shared__ __align__(16) float wbuf[CIN0 * 64];
  const int bs = blockIdx.x, t = threadIdx.x;
  build_x0(actA, xyz, points, knn_idx, newxyz, bs, t);
  loadw(wbuf, w0, CIN0 * 64, t);
  __syncthreads();
  matmul64<CIN0>(actA, wbuf, b0, outB, t);
  __syncthreads();
  norm_relu64(outB, scales, shifts, t);
  loadw(wbuf, w1, 64 * 64, t);
  __syncthreads();
  matmul64<64>(outB, wbuf, b1, actA, t);
  __syncthreads();
  stats64(actA, psum, psq, bs, 0, t);
}

__global__ __launch_bounds__(256) void passC_kernel(
    const float* __restrict__ xyz, const float* __restrict__ points,
    const float* __restrict__ newxyz, const int* __restrict__ knn_idx,
    const float* __restrict__ w0, const float* __restrict__ b0,
    const float* __restrict__ w1, const float* __restrict__ b1,
    const float* __restrict__ w2, const float* __restrict__ b2,
    const float* __restrict__ scales, const float* __restrict__ shifts,
    float* __restrict__ psum, float* __restrict__ psq,
    float* __restrict__ maxraw, float* __restrict__ minbuf) {
  __shared__ __align__(16) float actA[K_ * AST];
  __shared__ __align__(16) float outB[K_ * AST];
  __shared__ __align__(16) float wbuf[CIN0 * 64];
  const int bs = blockIdx.x, t = threadIdx.x;
  build_x0(actA, xyz, points, knn_idx, newxyz, bs, t);
  loadw(wbuf, w0, CIN0 * 64, t);
  __syncthreads();
  matmul64<CIN0>(actA, wbuf, b0, outB, t);
  __syncthreads();
  norm_relu64(outB, scales, shifts, t);
  loadw(wbuf, w1, 64 * 64, t);
  __syncthreads();
  matmul64<64>(outB, wbuf, b1, actA, t);
  __syncthreads();
  norm_relu64(actA, scales + 128, shifts + 128, t);
  loadw_half(wbuf, w2, 0, t);
  __syncthreads();
  matmul64<64>(actA, wbuf, b2, outB, t);
  __syncthreads();
  stats64(outB, psum, psq, bs, 0, t);
  minmax64(outB, maxraw, minbuf, bs, 0, t);
  loadw_half(wbuf, w2, 64, t);
  __syncthreads();
  matmul64<64>(actA, wbuf, b2 + 64, outB, t);
  __syncthreads();
  stats64(outB, psum, psq, bs, 64, t);
  minmax64(outB, maxraw, minbuf, bs, 64, t);
}

// ---------------- BN finalize ----------------
__global__ __launch_bounds__(256) void finalize_kernel(
    const float* __restrict__ psum, const float* __restrict__ psq,
    const float* __restrict__ g, const float* __restrict__ be,
    float* __restrict__ scale, float* __restrict__ shift) {
  const int ch = blockIdx.x, t = threadIdx.x;
  __shared__ float ss[256];
  __shared__ float sq[256];
  float s = 0.f, q = 0.f;
  for (int p = t; p < NBS; p += 256) {
    s += psum[(size_t)p * 128 + ch];
    q += psq[(size_t)p * 128 + ch];
  }
  ss[t] = s; sq[t] = q;
  __syncthreads();
  for (int off = 128; off >= 1; off >>= 1) {
    if (t < off) { ss[t] += ss[t + off]; sq[t] += sq[t + off]; }
    __syncthreads();
  }
  if (t == 0) {
    const float invN = 1.0f / (float)(B_ * S_ * K_);
    const float mean = ss[0] * invN;
    const float var = sq[0] * invN - mean * mean;
    const float sc = g[ch] / sqrtf(var + 1e-5f);
    scale[ch] = sc;
    shift[ch] = be[ch] - mean * sc;
  }
}

// ---------------- Final ----------------
__global__ __launch_bounds__(256) void final_kernel(
    const float* __restrict__ minbuf, const float* __restrict__ scale,
    const float* __restrict__ shift, float* __restrict__ out) {
  const int i = blockIdx.x * 256 + threadIdx.x;  // < B*S*128
  const int ch = i & 127;
  const float sc = scale[ch], sh = shift[ch];
  const float mx = out[NEWXYZ_FLOATS + i];
  const float mn = minbuf[i];
  const float v = sc * (sc >= 0.f ? mx : mn) + sh;
  out[NEWXYZ_FLOATS + i] = fmaxf(v, 0.f);
}

// ---------------- host ----------------
extern "C" void kernel_launch(void* const* d_in, const int* in_sizes, int n_in,
                              void* d_out, int out_size, void* d_ws, size_t ws_size,
                              hipStream_t stream) {
  const float* xyz = (const float*)d_in[0];
  const float* points = (const float*)d_in[1];
  const float* w0 = (const float*)d_in[2];
  const float* b0 = (const float*)d_in[3];
  const float* g0 = (const float*)d_in[4];
  const float* be0 = (const float*)d_in[5];
  const float* w1 = (const float*)d_in[6];
  const float* b1 = (const float*)d_in[7];
  const float* g1 = (const float*)d_in[8];
  const float* be1 = (const float*)d_in[9];
  const float* w2 = (const float*)d_in[10];
  const float* b2 = (const float*)d_in[11];
  const float* g2 = (const float*)d_in[12];
  const float* be2 = (const float*)d_in[13];
  float* out = (float*)d_out;
  float* newxyz = out;
  float* maxraw = out + NEWXYZ_FLOATS;

  float* ws = (float*)d_ws;
  const size_t NEED_FAST =
      (size_t)(524288 + 16384 * 2048 + 2 * NBS * 128 + 768 + NBS * 128) * 4;

  fps_kernel<<<B_, 256, 0, stream>>>(xyz, newxyz);

  if (ws_size >= NEED_FAST) {
    int* knn_idx = (int*)ws;
    float* zbuf = ws + 524288;
    float* psum = zbuf + (size_t)16384 * 2048;
    float* psq = psum + (size_t)NBS * 128;
    float* scales = psq + (size_t)NBS * 128;
    float* shifts = scales + 384;
    float* minbuf = shifts + 384;
    knn_kernel<<<NBS / 4, 256, 0, stream>>>(xyz, newxyz, knn_idx);
    passA4_kernel<<<NBS / QB, 256, 0, stream>>>(xyz, points, newxyz, knn_idx, w0, b0,
                                                psum, psq, zbuf);
    finalize_kernel<<<64, 256, 0, stream>>>(psum, psq, g0, be0, scales, shifts);
    passB4_kernel<<<NBS / QB, 256, 0, stream>>>(w1, b1, scales, shifts, psum, psq, zbuf);
    finalize_kernel<<<64, 256, 0, stream>>>(psum, psq, g1, be1, scales + 128, shifts + 128);
    passC4_kernel<<<NBS / QB, 256, 0, stream>>>(w2, b2, scales + 128, shifts + 128,
                                                psum, psq, maxraw, minbuf, zbuf);
    finalize_kernel<<<128, 256, 0, stream>>>(psum, psq, g2, be2, scales + 256, shifts + 256);
    final_kernel<<<(B_ * S_ * 128) / 256, 256, 0, stream>>>(minbuf, scales + 256,
                                                            shifts + 256, out);
  } else {
    int* knn_idx = (int*)ws;
    float* psum = ws + 524288;
    float* psq = psum + (size_t)NBS * 128;
    float* scales = psq + (size_t)NBS * 128;
    float* shifts = scales + 384;
    float* minbuf = shifts + 384;
    knn_kernel<<<NBS / 4, 256, 0, stream>>>(xyz, newxyz, knn_idx);
    passA_kernel<<<NBS, 256, 0, stream>>>(xyz, points, newxyz, knn_idx, w0, b0, psum, psq);
    finalize_kernel<<<64, 256, 0, stream>>>(psum, psq, g0, be0, scales, shifts);
    passB_kernel<<<NBS, 256, 0, stream>>>(xyz, points, newxyz, knn_idx, w0, b0, w1, b1,
                                          scales, shifts, psum, psq);
    finalize_kernel<<<64, 256, 0, stream>>>(psum, psq, g1, be1, scales + 128, shifts + 128);
    passC_kernel<<<NBS, 256, 0, stream>>>(xyz, points, newxyz, knn_idx, w0, b0, w1, b1, w2, b2,
                                          scales, shifts, psum, psq, maxraw, minbuf);
    finalize_kernel<<<128, 256, 0, stream>>>(psum, psq, g2, be2, scales + 256, shifts + 256);
    final_kernel<<<(B_ * S_ * 128) / 256, 256, 0, stream>>>(minbuf, scales + 256,
                                                            shifts + 256, out);
  }
}